// Round 1
// baseline (840.161 us; speedup 1.0000x reference)
//
#include <hip/hip_runtime.h>
#include <hip/hip_bf16.h>

// Problem constants (setup_inputs is fixed: episodes == 25, verified by out_size)
#define NPOS 1296              // 36*36 oscillators
#define BATCH 512
#define STEPS 25
#define PH_STRIDE (BATCH * NPOS)            // 663552
#define PH_TOTAL ((STEPS + 1) * PH_STRIDE)  // 17252352
#define FC_K 3456
#define FC_N 864
#define FC_NPAD 896
#define FC_M 6144

typedef float f32x4 __attribute__((ext_vector_type(4)));
typedef __bf16 bf16x8 __attribute__((ext_vector_type(8)));

__device__ __forceinline__ ushort f2bf(float f) {
  union { float f; unsigned u; } v; v.f = f;
  unsigned r = v.u + 0x7FFFu + ((v.u >> 16) & 1u);  // RNE
  return (ushort)(r >> 16);
}
__device__ __forceinline__ float bf2f(ushort h) {
  union { unsigned u; float f; } v; v.u = ((unsigned)h) << 16; return v.f;
}

// ---------------- conv1 (1->8) + conv2 (8->16), one block per image ----------------
__global__ __launch_bounds__(256) void conv12_kernel(
    const float* __restrict__ in, const float* __restrict__ w1, const float* __restrict__ b1,
    const float* __restrict__ w2, const float* __restrict__ b2, ushort* __restrict__ c2out) {
  __shared__ float sIn[NPOS];
  __shared__ ushort sC1[8 * NPOS];
  const int b = blockIdx.x, tid = threadIdx.x;
  {
    const float4* src = (const float4*)(in + (size_t)b * NPOS);
    float4* dst = (float4*)sIn;
    for (int i = tid; i < NPOS / 4; i += 256) dst[i] = src[i];
  }
  __syncthreads();
  for (int p = tid; p < NPOS; p += 256) {
    const int y = p / 36, x = p - y * 36;
    float acc[8];
#pragma unroll
    for (int co = 0; co < 8; ++co) acc[co] = b1[co];
#pragma unroll
    for (int dy = 0; dy < 3; ++dy) {
      const int iy = y + dy - 1;
#pragma unroll
      for (int dx = 0; dx < 3; ++dx) {
        const int ix = x + dx - 1;
        const bool ok = ((unsigned)iy < 36u) & ((unsigned)ix < 36u);
        float v = sIn[ok ? iy * 36 + ix : 0];
        v = ok ? v : 0.f;
#pragma unroll
        for (int co = 0; co < 8; ++co) acc[co] = fmaf(w1[co * 9 + dy * 3 + dx], v, acc[co]);
      }
    }
#pragma unroll
    for (int co = 0; co < 8; ++co) sC1[co * NPOS + p] = f2bf(fmaxf(acc[co], 0.f));
  }
  __syncthreads();
  ushort* outb = c2out + (size_t)b * (16 * NPOS);
  for (int p = tid; p < NPOS; p += 256) {
    const int y = p / 36, x = p - y * 36;
    float acc[16];
#pragma unroll
    for (int co = 0; co < 16; ++co) acc[co] = b2[co];
#pragma unroll
    for (int ci = 0; ci < 8; ++ci) {
#pragma unroll
      for (int dy = 0; dy < 3; ++dy) {
        const int iy = y + dy - 1;
#pragma unroll
        for (int dx = 0; dx < 3; ++dx) {
          const int ix = x + dx - 1;
          const bool ok = ((unsigned)iy < 36u) & ((unsigned)ix < 36u);
          float v = bf2f(sC1[ci * NPOS + (ok ? iy * 36 + ix : 0)]);
          v = ok ? v : 0.f;
#pragma unroll
          for (int co = 0; co < 16; ++co)
            acc[co] = fmaf(w2[(co * 8 + ci) * 9 + dy * 3 + dx], v, acc[co]);
        }
      }
    }
#pragma unroll
    for (int co = 0; co < 16; ++co) outb[co * NPOS + p] = f2bf(fmaxf(acc[co], 0.f));
  }
}

// ---------------- conv3 (16->32) + sigmoid, one block per image ----------------
__global__ __launch_bounds__(256) void conv3_kernel(
    const ushort* __restrict__ c2, const float* __restrict__ w3, const float* __restrict__ b3,
    ushort* __restrict__ aout) {
  __shared__ ushort sC2[16 * NPOS];
  const int b = blockIdx.x, tid = threadIdx.x;
  {
    const uint4* src = (const uint4*)(c2 + (size_t)b * (16 * NPOS));
    uint4* dst = (uint4*)sC2;
    for (int i = tid; i < 16 * NPOS / 8; i += 256) dst[i] = src[i];
  }
  __syncthreads();
  ushort* outb = aout + (size_t)b * (32 * NPOS);
  for (int p = tid; p < NPOS; p += 256) {
    const int y = p / 36, x = p - y * 36;
    float acc[32];
#pragma unroll
    for (int co = 0; co < 32; ++co) acc[co] = b3[co];
#pragma unroll 4
    for (int ci = 0; ci < 16; ++ci) {
#pragma unroll
      for (int dy = 0; dy < 3; ++dy) {
        const int iy = y + dy - 1;
#pragma unroll
        for (int dx = 0; dx < 3; ++dx) {
          const int ix = x + dx - 1;
          const bool ok = ((unsigned)iy < 36u) & ((unsigned)ix < 36u);
          float v = bf2f(sC2[ci * NPOS + (ok ? iy * 36 + ix : 0)]);
          v = ok ? v : 0.f;
#pragma unroll
          for (int co = 0; co < 32; ++co)
            acc[co] = fmaf(w3[(co * 16 + ci) * 9 + dy * 3 + dx], v, acc[co]);
        }
      }
    }
#pragma unroll
    for (int co = 0; co < 32; ++co) {
      const float s = 1.f / (1.f + __expf(-acc[co]));
      outb[co * NPOS + p] = f2bf(s);
    }
  }
}

// ---------------- fc_w (864x3456 f32) -> bf16, rows padded to 896 with zeros ----------------
__global__ __launch_bounds__(256) void wcvt_kernel(const float* __restrict__ w, ushort* __restrict__ wb) {
  const int idx = blockIdx.x * 256 + threadIdx.x;
  if (idx >= FC_NPAD * FC_K) return;
  const int n = idx / FC_K;
  wb[idx] = (n < FC_N) ? f2bf(w[idx]) : (ushort)0;
}

// ---------------- bf16 NT GEMM: C[m][n] = sum_k A[m][k]*Bt[n][k] + bias[n] ----------------
// 128x128 tile, BK=32, 4 waves of 64x64 (4x4 of 16x16x32 MFMA). M=6144, Npad=896, K=3456.
__global__ __launch_bounds__(256) void gemm_kernel(
    const ushort* __restrict__ A, const ushort* __restrict__ Bt,
    const float* __restrict__ bias, float* __restrict__ C) {
  __shared__ __align__(16) ushort sA[128 * 32];
  __shared__ __align__(16) ushort sB[128 * 32];
  const int tid = threadIdx.x;
  const int bn = blockIdx.x, bm = blockIdx.y;
  const int row0 = bm * 128, col0 = bn * 128;
  const int wave = tid >> 6, lane = tid & 63;
  const int wr = (wave >> 1) * 64, wc = (wave & 1) * 64;
  const int quad = lane >> 4, l16 = lane & 15;
  const int srow = tid >> 2;       // 0..63: tile row of this thread's 16B staging chunk
  const int skk = (tid & 3) * 8;   // element offset within the 32-wide k slab
  f32x4 acc[4][4] = {};
  const ushort* Abase = A + ((size_t)row0 + srow) * FC_K + skk;
  const ushort* Bbase = Bt + ((size_t)col0 + srow) * FC_K + skk;
  for (int kt = 0; kt < FC_K / 32; ++kt) {
    const int k0 = kt * 32;
    const uint4 a0 = *(const uint4*)(Abase + k0);
    const uint4 a1 = *(const uint4*)(Abase + (size_t)64 * FC_K + k0);
    const uint4 bv0 = *(const uint4*)(Bbase + k0);
    const uint4 bv1 = *(const uint4*)(Bbase + (size_t)64 * FC_K + k0);
    __syncthreads();
    *(uint4*)(sA + tid * 8) = a0;
    *(uint4*)(sA + tid * 8 + 2048) = a1;
    *(uint4*)(sB + tid * 8) = bv0;
    *(uint4*)(sB + tid * 8 + 2048) = bv1;
    __syncthreads();
    bf16x8 af[4], bfr[4];
#pragma unroll
    for (int t = 0; t < 4; ++t) {
      af[t] = *(const bf16x8*)(sA + (wr + t * 16 + l16) * 32 + quad * 8);
      bfr[t] = *(const bf16x8*)(sB + (wc + t * 16 + l16) * 32 + quad * 8);
    }
#pragma unroll
    for (int tm = 0; tm < 4; ++tm)
#pragma unroll
      for (int tn = 0; tn < 4; ++tn)
        acc[tm][tn] = __builtin_amdgcn_mfma_f32_16x16x32_bf16(af[tm], bfr[tn], acc[tm][tn], 0, 0, 0);
  }
#pragma unroll
  for (int tn = 0; tn < 4; ++tn) {
    const int col = col0 + wc + tn * 16 + l16;
    if (col < FC_N) {
      const float bv = bias[col];
#pragma unroll
      for (int tm = 0; tm < 4; ++tm) {
#pragma unroll
        for (int r = 0; r < 4; ++r) {
          const int row = row0 + wr + tm * 16 + quad * 4 + r;
          C[(size_t)row * FC_N + col] = acc[tm][tn][r] + bv;
        }
      }
    }
  }
}

// ---------------- Kuramoto: one block per batch, 25 steps ----------------
// sin(t_j - t_i) = sin t_j cos t_i - cos t_j sin t_i -> 1 sincos per oscillator per step.
__global__ __launch_bounds__(256) void kuramoto_kernel(
    const float* __restrict__ ph0, const int* __restrict__ conn,
    const float* __restrict__ cpl, float* __restrict__ out) {
  __shared__ float ph[NPOS];
  __shared__ float2 sc[NPOS];
  const int b = blockIdx.x, tid = threadIdx.x;
  int rj[6][8];
  float rc[6][8];
#pragma unroll
  for (int s = 0; s < 6; ++s) {
    const int i = tid + s * 256;
    if (i < NPOS) {
      const float p = ph0[(size_t)b * NPOS + i];
      ph[i] = p;
      out[(size_t)b * NPOS + i] = p;  // step 0 = initial phase
      const size_t base = (size_t)b * (NPOS * 8) + (size_t)i * 8;
      const int4 j0 = *(const int4*)(conn + base);
      const int4 j1 = *(const int4*)(conn + base + 4);
      const float4 c0 = *(const float4*)(cpl + base);
      const float4 c1 = *(const float4*)(cpl + base + 4);
      rj[s][0] = j0.x; rj[s][1] = j0.y; rj[s][2] = j0.z; rj[s][3] = j0.w;
      rj[s][4] = j1.x; rj[s][5] = j1.y; rj[s][6] = j1.z; rj[s][7] = j1.w;
      rc[s][0] = c0.x; rc[s][1] = c0.y; rc[s][2] = c0.z; rc[s][3] = c0.w;
      rc[s][4] = c1.x; rc[s][5] = c1.y; rc[s][6] = c1.z; rc[s][7] = c1.w;
    } else {
#pragma unroll
      for (int k = 0; k < 8; ++k) { rj[s][k] = 0; rc[s][k] = 0.f; }
    }
  }
  float ep = 0.1f;
  for (int t = 0; t < STEPS; ++t) {
    __syncthreads();
    for (int i = tid; i < NPOS; i += 256) {
      float s, c;
      __sincosf(ph[i], &s, &c);
      sc[i] = make_float2(s, c);
    }
    __syncthreads();
    float* op = out + (size_t)(t + 1) * PH_STRIDE + (size_t)b * NPOS;
#pragma unroll
    for (int s = 0; s < 6; ++s) {
      const int i = tid + s * 256;
      if (i < NPOS) {
        float ss = 0.f, cs = 0.f;
#pragma unroll
        for (int k = 0; k < 8; ++k) {
          const float2 v = sc[rj[s][k]];
          ss = fmaf(rc[s][k], v.x, ss);
          cs = fmaf(rc[s][k], v.y, cs);
        }
        const float2 me = sc[i];
        const float np = ph[i] + ep * (me.y * ss - me.x * cs);
        ph[i] = np;
        op[i] = np;
      }
    }
    ep = ep * (1.0f - 0.02f * (float)t);  // ep -= 0.5*t*ep/25
  }
}

extern "C" void kernel_launch(void* const* d_in, const int* in_sizes, int n_in,
                              void* d_out, int out_size, void* d_ws, size_t ws_size,
                              hipStream_t stream) {
  const float* input = (const float*)d_in[0];
  const float* ph0   = (const float*)d_in[1];
  const int*   conn  = (const int*)d_in[2];
  // d_in[3] = episodes (always 25)
  const float* w1 = (const float*)d_in[4];
  const float* b1 = (const float*)d_in[5];
  const float* w2 = (const float*)d_in[6];
  const float* b2 = (const float*)d_in[7];
  const float* w3 = (const float*)d_in[8];
  const float* b3 = (const float*)d_in[9];
  const float* fcw = (const float*)d_in[10];
  const float* fcb = (const float*)d_in[11];
  float* out = (float*)d_out;

  // workspace layout (bytes): c2 bf16 [21,233,664) | A bf16 [42,467,328) | Wpad bf16 [6,193,152)
  ushort* c2buf = (ushort*)d_ws;
  ushort* Abuf  = (ushort*)((char*)d_ws + 21233664);
  ushort* Wbuf  = (ushort*)((char*)d_ws + 63700992);
  float* fcout = out + PH_TOTAL;

  wcvt_kernel<<<(FC_NPAD * FC_K) / 256, 256, 0, stream>>>(fcw, Wbuf);
  conv12_kernel<<<BATCH, 256, 0, stream>>>(input, w1, b1, w2, b2, c2buf);
  conv3_kernel<<<BATCH, 256, 0, stream>>>(c2buf, w3, b3, Abuf);
  gemm_kernel<<<dim3(FC_NPAD / 128, FC_M / 128), 256, 0, stream>>>(Abuf, Wbuf, fcb, fcout);
  kuramoto_kernel<<<BATCH, 256, 0, stream>>>(ph0, conn, fcout, out);
}

// Round 2
// 813.217 us; speedup vs baseline: 1.0331x; 1.0331x over previous
//
#include <hip/hip_runtime.h>
#include <hip/hip_bf16.h>

#define NPOS 1296              // 36*36 oscillators
#define BATCH 512
#define STEPS 25
#define PH_STRIDE (BATCH * NPOS)            // 663552
#define PH_TOTAL ((STEPS + 1) * PH_STRIDE)  // 17252352
#define FC_K 3456
#define FC_N 864
#define FC_NPAD 896
#define FC_M 6144

typedef float f32x4 __attribute__((ext_vector_type(4)));
typedef __bf16 bf16x8 __attribute__((ext_vector_type(8)));

__device__ __forceinline__ ushort f2bf(float f) {
  union { float f; unsigned u; } v; v.f = f;
  unsigned r = v.u + 0x7FFFu + ((v.u >> 16) & 1u);  // RNE
  return (ushort)(r >> 16);
}
__device__ __forceinline__ float bf2f(ushort h) {
  union { unsigned u; float f; } v; v.u = ((unsigned)h) << 16; return v.f;
}

// ---------------- conv1 (1->8) + conv2 (8->16), one block per (image, 12-row band) ---------
// Zero-padded LDS rows (width 40, interior cols 2..37) -> no bounds checks in inner loops.
__global__ __launch_bounds__(256) void conv12_kernel(
    const float* __restrict__ in, const float* __restrict__ w1, const float* __restrict__ b1,
    const float* __restrict__ w2, const float* __restrict__ b2, ushort* __restrict__ c2out) {
  __shared__ __align__(16) float sIn[16][40];       // input rows r0-2 .. r0+13
  __shared__ __align__(16) ushort sC1[8][14][40];   // c1 rows r0-1 .. r0+12
  const int b = blockIdx.x, band = blockIdx.y, tid = threadIdx.x;
  const int r0 = band * 12;
  for (int i = tid; i < 16 * 40; i += 256) ((float*)sIn)[i] = 0.f;
  for (int i = tid; i < 8 * 14 * 40 / 2; i += 256) ((uint*)sC1)[i] = 0u;
  __syncthreads();
  // load input band (interior only; pads stay zero)
  for (int i = tid; i < 16 * 18; i += 256) {
    const int r = i / 18, c = i - r * 18;
    const int gy = r0 - 2 + r;
    if ((unsigned)gy < 36u) {
      const float2 v = *(const float2*)(in + (size_t)b * NPOS + gy * 36 + 2 * c);
      *(float2*)&sIn[r][2 + 2 * c] = v;
    }
  }
  __syncthreads();
  // conv1 on 14 rows (r0-1 .. r0+12)
  for (int i = tid; i < 14 * 36; i += 256) {
    const int lr = i / 36, x = i - lr * 36;
    const int gy = r0 - 1 + lr;
    if ((unsigned)gy < 36u) {
      float acc[8];
#pragma unroll
      for (int co = 0; co < 8; ++co) acc[co] = b1[co];
#pragma unroll
      for (int dy = 0; dy < 3; ++dy)
#pragma unroll
        for (int dx = 0; dx < 3; ++dx) {
          const float v = sIn[lr + dy][1 + x + dx];
#pragma unroll
          for (int co = 0; co < 8; ++co) acc[co] = fmaf(w1[co * 9 + dy * 3 + dx], v, acc[co]);
        }
#pragma unroll
      for (int co = 0; co < 8; ++co) sC1[co][lr][2 + x] = f2bf(fmaxf(acc[co], 0.f));
    }
  }
  __syncthreads();
  // conv2 on 12 rows (r0 .. r0+11)
  ushort* outb = c2out + (size_t)b * (16 * NPOS);
  for (int i = tid; i < 12 * 36; i += 256) {
    const int oy = i / 36, x = i - oy * 36;
    float acc[16];
#pragma unroll
    for (int co = 0; co < 16; ++co) acc[co] = b2[co];
#pragma unroll
    for (int ci = 0; ci < 8; ++ci)
#pragma unroll
      for (int dy = 0; dy < 3; ++dy)
#pragma unroll
        for (int dx = 0; dx < 3; ++dx) {
          const float v = bf2f(sC1[ci][oy + dy][1 + x + dx]);
#pragma unroll
          for (int co = 0; co < 16; ++co)
            acc[co] = fmaf(w2[(co * 8 + ci) * 9 + dy * 3 + dx], v, acc[co]);
        }
    const int p = (r0 + oy) * 36 + x;
#pragma unroll
    for (int co = 0; co < 16; ++co) outb[co * NPOS + p] = f2bf(fmaxf(acc[co], 0.f));
  }
}

// ---------------- conv3 (16->32) + sigmoid, one block per (image, 12-row band) ----------------
__global__ __launch_bounds__(256) void conv3_kernel(
    const ushort* __restrict__ c2, const float* __restrict__ w3, const float* __restrict__ b3,
    ushort* __restrict__ aout) {
  __shared__ __align__(16) ushort sC2[16][14][40];  // c2 rows r0-1 .. r0+12, zero-padded
  const int b = blockIdx.x, band = blockIdx.y, tid = threadIdx.x;
  const int r0 = band * 12;
  for (int i = tid; i < 16 * 14 * 40 / 2; i += 256) ((uint*)sC2)[i] = 0u;
  __syncthreads();
  const ushort* src = c2 + (size_t)b * (16 * NPOS);
  for (int i = tid; i < 16 * 14 * 18; i += 256) {
    const int ci = i / 252, rem = i - ci * 252;
    const int lr = rem / 18, c = rem - lr * 18;
    const int gy = r0 - 1 + lr;
    if ((unsigned)gy < 36u) {
      const uint v = *(const uint*)(src + ci * NPOS + gy * 36 + 2 * c);
      *(uint*)&sC2[ci][lr][2 + 2 * c] = v;
    }
  }
  __syncthreads();
  ushort* outb = aout + (size_t)b * (32 * NPOS);
  for (int i = tid; i < 12 * 36; i += 256) {
    const int oy = i / 36, x = i - oy * 36;
    float acc[32];
#pragma unroll
    for (int co = 0; co < 32; ++co) acc[co] = b3[co];
#pragma unroll 4
    for (int ci = 0; ci < 16; ++ci)
#pragma unroll
      for (int dy = 0; dy < 3; ++dy)
#pragma unroll
        for (int dx = 0; dx < 3; ++dx) {
          const float v = bf2f(sC2[ci][oy + dy][1 + x + dx]);
#pragma unroll
          for (int co = 0; co < 32; ++co)
            acc[co] = fmaf(w3[(co * 16 + ci) * 9 + dy * 3 + dx], v, acc[co]);
        }
    const int p = (r0 + oy) * 36 + x;
#pragma unroll
    for (int co = 0; co < 32; ++co) {
      const float s = 1.f / (1.f + __expf(-acc[co]));
      outb[co * NPOS + p] = f2bf(s);
    }
  }
}

// ---------------- fc_w (864x3456 f32) -> bf16, rows padded to 896 with zeros ----------------
__global__ __launch_bounds__(256) void wcvt_kernel(const float* __restrict__ w, ushort* __restrict__ wb) {
  const int idx = blockIdx.x * 256 + threadIdx.x;
  if (idx >= FC_NPAD * FC_K) return;
  const int n = idx / FC_K;
  wb[idx] = (n < FC_N) ? f2bf(w[idx]) : (ushort)0;
}

// ---------------- bf16 NT GEMM: C[m][n] = sum_k A[m][k]*Bt[n][k] + bias[n] ----------------
// 64x128 tile, BK=32, 4 waves each 32x64 (2x4 of 16x16x32 MFMA). Grid 672 blocks (2.6/CU).
__global__ __launch_bounds__(256) void gemm_kernel(
    const ushort* __restrict__ A, const ushort* __restrict__ Bt,
    const float* __restrict__ bias, float* __restrict__ C) {
  __shared__ __align__(16) ushort sA[64 * 32];
  __shared__ __align__(16) ushort sB[128 * 32];
  const int tid = threadIdx.x;
  const int bn = blockIdx.x, bm = blockIdx.y;
  const int row0 = bm * 64, col0 = bn * 128;
  const int wave = tid >> 6, lane = tid & 63;
  const int wr = (wave >> 1) * 32, wc = (wave & 1) * 64;
  const int quad = lane >> 4, l16 = lane & 15;
  const int srow = tid >> 2;       // 0..63
  const int skk = (tid & 3) * 8;
  f32x4 acc[2][4] = {};
  const ushort* Abase = A + ((size_t)row0 + srow) * FC_K + skk;
  const ushort* Bbase = Bt + ((size_t)col0 + srow) * FC_K + skk;
  for (int kt = 0; kt < FC_K / 32; ++kt) {
    const int k0 = kt * 32;
    const uint4 a0 = *(const uint4*)(Abase + k0);
    const uint4 bv0 = *(const uint4*)(Bbase + k0);
    const uint4 bv1 = *(const uint4*)(Bbase + (size_t)64 * FC_K + k0);
    __syncthreads();
    *(uint4*)(sA + tid * 8) = a0;
    *(uint4*)(sB + tid * 8) = bv0;
    *(uint4*)(sB + tid * 8 + 2048) = bv1;
    __syncthreads();
    bf16x8 af[2], bfr[4];
#pragma unroll
    for (int t = 0; t < 2; ++t)
      af[t] = *(const bf16x8*)(sA + (wr + t * 16 + l16) * 32 + quad * 8);
#pragma unroll
    for (int t = 0; t < 4; ++t)
      bfr[t] = *(const bf16x8*)(sB + (wc + t * 16 + l16) * 32 + quad * 8);
#pragma unroll
    for (int tm = 0; tm < 2; ++tm)
#pragma unroll
      for (int tn = 0; tn < 4; ++tn)
        acc[tm][tn] = __builtin_amdgcn_mfma_f32_16x16x32_bf16(af[tm], bfr[tn], acc[tm][tn], 0, 0, 0);
  }
#pragma unroll
  for (int tn = 0; tn < 4; ++tn) {
    const int col = col0 + wc + tn * 16 + l16;
    if (col < FC_N) {
      const float bv = bias[col];
#pragma unroll
      for (int tm = 0; tm < 2; ++tm) {
#pragma unroll
        for (int r = 0; r < 4; ++r) {
          const int row = row0 + wr + tm * 16 + quad * 4 + r;
          C[(size_t)row * FC_N + col] = acc[tm][tn][r] + bv;
        }
      }
    }
  }
}

// ---------------- Kuramoto: one block (512 threads) per batch, 25 steps ----------------
__global__ __launch_bounds__(512) void kuramoto_kernel(
    const float* __restrict__ ph0, const int* __restrict__ conn,
    const float* __restrict__ cpl, float* __restrict__ out) {
  __shared__ float ph[NPOS];
  __shared__ float2 sc[NPOS];
  const int b = blockIdx.x, tid = threadIdx.x;
  int rj[3][8];
  float rc[3][8];
#pragma unroll
  for (int s = 0; s < 3; ++s) {
    const int i = tid + s * 512;
    if (i < NPOS) {
      const float p = ph0[(size_t)b * NPOS + i];
      ph[i] = p;
      out[(size_t)b * NPOS + i] = p;  // step 0 = initial phase
      const size_t base = (size_t)b * (NPOS * 8) + (size_t)i * 8;
      const int4 j0 = *(const int4*)(conn + base);
      const int4 j1 = *(const int4*)(conn + base + 4);
      const float4 c0 = *(const float4*)(cpl + base);
      const float4 c1 = *(const float4*)(cpl + base + 4);
      rj[s][0] = j0.x; rj[s][1] = j0.y; rj[s][2] = j0.z; rj[s][3] = j0.w;
      rj[s][4] = j1.x; rj[s][5] = j1.y; rj[s][6] = j1.z; rj[s][7] = j1.w;
      rc[s][0] = c0.x; rc[s][1] = c0.y; rc[s][2] = c0.z; rc[s][3] = c0.w;
      rc[s][4] = c1.x; rc[s][5] = c1.y; rc[s][6] = c1.z; rc[s][7] = c1.w;
    } else {
#pragma unroll
      for (int k = 0; k < 8; ++k) { rj[s][k] = 0; rc[s][k] = 0.f; }
    }
  }
  float ep = 0.1f;
  for (int t = 0; t < STEPS; ++t) {
    __syncthreads();
    for (int i = tid; i < NPOS; i += 512) {
      float s, c;
      __sincosf(ph[i], &s, &c);
      sc[i] = make_float2(s, c);
    }
    __syncthreads();
    float* op = out + (size_t)(t + 1) * PH_STRIDE + (size_t)b * NPOS;
#pragma unroll
    for (int s = 0; s < 3; ++s) {
      const int i = tid + s * 512;
      if (i < NPOS) {
        float ss = 0.f, cs = 0.f;
#pragma unroll
        for (int k = 0; k < 8; ++k) {
          const float2 v = sc[rj[s][k]];
          ss = fmaf(rc[s][k], v.x, ss);
          cs = fmaf(rc[s][k], v.y, cs);
        }
        const float2 me = sc[i];
        const float np = ph[i] + ep * (me.y * ss - me.x * cs);
        ph[i] = np;
        op[i] = np;
      }
    }
    ep = ep * (1.0f - 0.02f * (float)t);  // ep -= 0.5*t*ep/25
  }
}

extern "C" void kernel_launch(void* const* d_in, const int* in_sizes, int n_in,
                              void* d_out, int out_size, void* d_ws, size_t ws_size,
                              hipStream_t stream) {
  const float* input = (const float*)d_in[0];
  const float* ph0   = (const float*)d_in[1];
  const int*   conn  = (const int*)d_in[2];
  // d_in[3] = episodes (always 25)
  const float* w1 = (const float*)d_in[4];
  const float* b1 = (const float*)d_in[5];
  const float* w2 = (const float*)d_in[6];
  const float* b2 = (const float*)d_in[7];
  const float* w3 = (const float*)d_in[8];
  const float* b3 = (const float*)d_in[9];
  const float* fcw = (const float*)d_in[10];
  const float* fcb = (const float*)d_in[11];
  float* out = (float*)d_out;

  // workspace layout (bytes): c2 bf16 [0,21233664) | A bf16 [21233664,63700992) | Wpad bf16
  ushort* c2buf = (ushort*)d_ws;
  ushort* Abuf  = (ushort*)((char*)d_ws + 21233664);
  ushort* Wbuf  = (ushort*)((char*)d_ws + 63700992);
  float* fcout = out + PH_TOTAL;

  wcvt_kernel<<<(FC_NPAD * FC_K) / 256, 256, 0, stream>>>(fcw, Wbuf);
  conv12_kernel<<<dim3(BATCH, 3), 256, 0, stream>>>(input, w1, b1, w2, b2, c2buf);
  conv3_kernel<<<dim3(BATCH, 3), 256, 0, stream>>>(c2buf, w3, b3, Abuf);
  gemm_kernel<<<dim3(FC_NPAD / 128, FC_M / 64), 256, 0, stream>>>(Abuf, Wbuf, fcb, fcout);
  kuramoto_kernel<<<BATCH, 512, 0, stream>>>(ph0, conn, fcout, out);
}

// Round 3
// 286.912 us; speedup vs baseline: 2.9283x; 2.8344x over previous
//
#include <hip/hip_runtime.h>
#include <hip/hip_bf16.h>

#define NPOS 1296              // 36*36 oscillators
#define BATCH 512
#define STEPS 25
#define PH_STRIDE (BATCH * NPOS)            // 663552
#define PH_TOTAL ((STEPS + 1) * PH_STRIDE)  // 17252352
#define FC_K 3456
#define FC_N 864
#define FC_NPAD 896
#define FC_M 6144

typedef float f32x4 __attribute__((ext_vector_type(4)));
typedef __bf16 bf16x8 __attribute__((ext_vector_type(8)));

__device__ __forceinline__ ushort f2bf(float f) {
  union { float f; unsigned u; } v; v.f = f;
  unsigned r = v.u + 0x7FFFu + ((v.u >> 16) & 1u);  // RNE
  return (ushort)(r >> 16);
}
__device__ __forceinline__ float bf2f(ushort h) {
  union { unsigned u; float f; } v; v.u = ((unsigned)h) << 16; return v.f;
}

__device__ __forceinline__ void async_copy16(void* lds, const void* g) {
  __builtin_amdgcn_global_load_lds(
      (const __attribute__((address_space(1))) unsigned*)g,
      (__attribute__((address_space(3))) unsigned*)lds, 16, 0, 0);
}

// ---------------- weight prep: transpose to MFMA-friendly [co][k] layouts ----------------
// w1t: [9][8] f32 (slice-major, co contiguous)
// w2t: [16 co][96 k] bf16, k=(dy*3+dx)*8+ci, zeros for k>=72
// w3t: [32 co][160 k] bf16, k=(dy*3+dx)*16+ci, zeros for k>=144
__global__ __launch_bounds__(256) void wprep_kernel(
    const float* __restrict__ w1, const float* __restrict__ w2, const float* __restrict__ w3,
    float* __restrict__ w1t, ushort* __restrict__ w2t, ushort* __restrict__ w3t) {
  const int tid = threadIdx.x;
  for (int i = tid; i < 72; i += 256) {
    const int s = i / 8, co = i - s * 8;
    w1t[i] = w1[co * 9 + s];
  }
  for (int i = tid; i < 16 * 96; i += 256) {
    const int co = i / 96, k = i - co * 96;
    const int s = k / 8, ci = k - s * 8;
    w2t[i] = (k < 72) ? f2bf(w2[(co * 8 + ci) * 9 + s]) : (ushort)0;
  }
  for (int i = tid; i < 32 * 160; i += 256) {
    const int co = i / 160, k = i - co * 160;
    const int s = k / 16, ci = k - s * 16;
    w3t[i] = (k < 144) ? f2bf(w3[(co * 16 + ci) * 9 + s]) : (ushort)0;
  }
}

// ---------------- fused conv1(VALU) + conv2(MFMA) + conv3(MFMA+sigmoid) ----------------
// One block per (image, 12-row band). LDS tiles channel-interleaved + zero-padded so the
// MFMA A-fragment (im2col) is a single ds_read_b128 per k-slice pair.
__global__ __launch_bounds__(256, 4) void conv_fused_kernel(
    const float* __restrict__ in, const float* __restrict__ w1t, const float* __restrict__ b1,
    const ushort* __restrict__ w2t, const float* __restrict__ b2,
    const ushort* __restrict__ w3t, const float* __restrict__ b3,
    ushort* __restrict__ aout) {
  __shared__ __align__(16) float sIn[18][40];          // input rows r0-3..r0+14, col x at x+2
  __shared__ __align__(16) ushort sC1[18][40][8];      // c1 rows r0-2..r0+13 (rows 16,17 zero)
  __shared__ __align__(16) ushort sC2[16][40][16];     // c2 rows r0-1..r0+12 (rows 14,15 zero)
  const int b = blockIdx.x, band = blockIdx.y, tid = threadIdx.x;
  const int r0 = band * 12;
  const int wave = tid >> 6, lane = tid & 63;
  const int quad = lane >> 4, l16 = lane & 15;
  // zero LDS (pads must be exactly 0)
  {
    const uint4 zz = make_uint4(0, 0, 0, 0);
    for (int i = tid; i < 180; i += 256) ((uint4*)sIn)[i] = zz;
    for (int i = tid; i < 720; i += 256) ((uint4*)sC1)[i] = zz;
    for (int i = tid; i < 1280; i += 256) ((uint4*)sC2)[i] = zz;
  }
  __syncthreads();
  // stage input rows r0-3..r0+14 into cols 2..37
  for (int i = tid; i < 18 * 18; i += 256) {
    const int r = i / 18, c = i - r * 18;
    const int gy = r0 - 3 + r;
    if ((unsigned)gy < 36u)
      *(float2*)&sIn[r][2 + 2 * c] = *(const float2*)(in + (size_t)b * NPOS + gy * 36 + 2 * c);
  }
  __syncthreads();
  // conv1: produce c1 rows 0..15 (global r0-2..r0+13); write only valid global rows
  for (int i = tid; i < 16 * 36; i += 256) {
    const int lr = i / 36, x = i - lr * 36;
    float acc[8];
#pragma unroll
    for (int co = 0; co < 8; ++co) acc[co] = b1[co];
#pragma unroll
    for (int s = 0; s < 9; ++s) {
      const int dy = s / 3, dx = s - 3 * dy;
      const float v = sIn[lr + dy][x + 1 + dx];
#pragma unroll
      for (int co = 0; co < 8; ++co) acc[co] = fmaf(w1t[s * 8 + co], v, acc[co]);
    }
    const int g1 = r0 - 2 + lr;
    if ((unsigned)g1 < 36u) {
      uint4 pk;
      pk.x = (uint)f2bf(fmaxf(acc[0], 0.f)) | ((uint)f2bf(fmaxf(acc[1], 0.f)) << 16);
      pk.y = (uint)f2bf(fmaxf(acc[2], 0.f)) | ((uint)f2bf(fmaxf(acc[3], 0.f)) << 16);
      pk.z = (uint)f2bf(fmaxf(acc[4], 0.f)) | ((uint)f2bf(fmaxf(acc[5], 0.f)) << 16);
      pk.w = (uint)f2bf(fmaxf(acc[6], 0.f)) | ((uint)f2bf(fmaxf(acc[7], 0.f)) << 16);
      *(uint4*)&sC1[lr][x + 2][0] = pk;
    }
  }
  __syncthreads();
  // conv2 via MFMA: M=512 px (504 valid, 14 rows), N=16 co, K=96 (72 real)
  bf16x8 w2f[3];
#pragma unroll
  for (int f = 0; f < 3; ++f)
    w2f[f] = *(const bf16x8*)(w2t + l16 * 96 + f * 32 + quad * 8);
  const float bias2 = b2[l16];
  for (int chunk = wave; chunk < 32; chunk += 4) {
    const int m = chunk * 16 + l16;
    const int oy = m / 36, x = m - oy * 36;
    f32x4 acc = {0.f, 0.f, 0.f, 0.f};
#pragma unroll
    for (int f = 0; f < 3; ++f) {
      const int s0 = 4 * f + quad;          // k-slice: dy*3+dx (9..11 = zero-weight pad)
      const int dy = s0 / 3, dx = s0 - 3 * dy;
      const bf16x8 af = *(const bf16x8*)&sC1[oy + dy][x + 1 + dx][0];
      acc = __builtin_amdgcn_mfma_f32_16x16x32_bf16(af, w2f[f], acc, 0, 0, 0);
    }
#pragma unroll
    for (int r = 0; r < 4; ++r) {
      const int px = chunk * 16 + quad * 4 + r;
      const int oy2 = px / 36, x2 = px - oy2 * 36;
      const int g2 = r0 - 1 + oy2;
      if (px < 504 && (unsigned)g2 < 36u)
        sC2[oy2][x2 + 2][l16] = f2bf(fmaxf(acc[r] + bias2, 0.f));
    }
  }
  __syncthreads();
  // conv3 via MFMA: M=432 px (12 rows), N=32 co (2 tiles), K=160 (144 real)
  bf16x8 w3f[2][5];
#pragma unroll
  for (int t = 0; t < 2; ++t)
#pragma unroll
    for (int f = 0; f < 5; ++f)
      w3f[t][f] = *(const bf16x8*)(w3t + (t * 16 + l16) * 160 + f * 32 + quad * 8);
  const float bias3a = b3[l16], bias3b = b3[16 + l16];
  ushort* ob = aout + (size_t)b * (32 * NPOS) + r0 * 36;
  for (int chunk = wave; chunk < 27; chunk += 4) {
    const int m = chunk * 16 + l16;
    const int oy = m / 36, x = m - oy * 36;
    f32x4 acc0 = {0.f, 0.f, 0.f, 0.f}, acc1 = {0.f, 0.f, 0.f, 0.f};
#pragma unroll
    for (int f = 0; f < 5; ++f) {
      const int s0 = 2 * f + (quad >> 1);   // k-slice (9 = zero-weight pad)
      const int dy = s0 / 3, dx = s0 - 3 * dy;
      const bf16x8 af = *(const bf16x8*)&sC2[oy + dy][x + 1 + dx][(quad & 1) * 8];
      acc0 = __builtin_amdgcn_mfma_f32_16x16x32_bf16(af, w3f[0][f], acc0, 0, 0, 0);
      acc1 = __builtin_amdgcn_mfma_f32_16x16x32_bf16(af, w3f[1][f], acc1, 0, 0, 0);
    }
    const int pxb = chunk * 16 + quad * 4;
    ushort4 pk;
#pragma unroll
    for (int r = 0; r < 4; ++r)
      ((ushort*)&pk)[r] = f2bf(1.f / (1.f + __expf(-(acc0[r] + bias3a))));
    *(ushort4*)(ob + (size_t)l16 * NPOS + pxb) = pk;
#pragma unroll
    for (int r = 0; r < 4; ++r)
      ((ushort*)&pk)[r] = f2bf(1.f / (1.f + __expf(-(acc1[r] + bias3b))));
    *(ushort4*)(ob + (size_t)(16 + l16) * NPOS + pxb) = pk;
  }
}

// ---------------- fc_w (864x3456 f32) -> bf16, rows padded to 896 with zeros ----------------
__global__ __launch_bounds__(256) void wcvt_kernel(const float* __restrict__ w, ushort* __restrict__ wb) {
  const int idx = blockIdx.x * 256 + threadIdx.x;
  if (idx >= FC_NPAD * FC_K) return;
  const int n = idx / FC_K;
  wb[idx] = (n < FC_N) ? f2bf(w[idx]) : (ushort)0;
}

// ---------------- bf16 NT GEMM: C[m][n] = sum_k A[m][k]*Bt[n][k] + bias[n] ----------------
// 64x128 tile, BK=32, 4 waves each 32x64 (2x4 of 16x16x32 MFMA), global_load_lds staging.
__global__ __launch_bounds__(256) void gemm_kernel(
    const ushort* __restrict__ A, const ushort* __restrict__ Bt,
    const float* __restrict__ bias, float* __restrict__ C) {
  __shared__ __align__(16) ushort sA[64 * 32];
  __shared__ __align__(16) ushort sB[128 * 32];
  const int tid = threadIdx.x;
  const int bn = blockIdx.x, bm = blockIdx.y;
  const int row0 = bm * 64, col0 = bn * 128;
  const int wave = tid >> 6, lane = tid & 63;
  const int wr = (wave >> 1) * 32, wc = (wave & 1) * 64;
  const int quad = lane >> 4, l16 = lane & 15;
  const int srow = tid >> 2;       // 0..63
  const int skk = (tid & 3) * 8;
  f32x4 acc[2][4] = {};
  const ushort* Abase = A + ((size_t)row0 + srow) * FC_K + skk;
  const ushort* Bbase = Bt + ((size_t)col0 + srow) * FC_K + skk;
  ushort* sAw = sA + wave * 512;   // wave-uniform LDS dest: base + lane*16B == sA + tid*8
  ushort* sBw = sB + wave * 512;
  for (int kt = 0; kt < FC_K / 32; ++kt) {
    const int k0 = kt * 32;
    __syncthreads();
    async_copy16(sAw, Abase + k0);
    async_copy16(sBw, Bbase + k0);
    async_copy16(sBw + 2048, Bbase + (size_t)64 * FC_K + k0);
    __syncthreads();
    bf16x8 af[2], bfr[4];
#pragma unroll
    for (int t = 0; t < 2; ++t)
      af[t] = *(const bf16x8*)(sA + (wr + t * 16 + l16) * 32 + quad * 8);
#pragma unroll
    for (int t = 0; t < 4; ++t)
      bfr[t] = *(const bf16x8*)(sB + (wc + t * 16 + l16) * 32 + quad * 8);
#pragma unroll
    for (int tm = 0; tm < 2; ++tm)
#pragma unroll
      for (int tn = 0; tn < 4; ++tn)
        acc[tm][tn] = __builtin_amdgcn_mfma_f32_16x16x32_bf16(af[tm], bfr[tn], acc[tm][tn], 0, 0, 0);
  }
#pragma unroll
  for (int tn = 0; tn < 4; ++tn) {
    const int col = col0 + wc + tn * 16 + l16;
    if (col < FC_N) {
      const float bv = bias[col];
#pragma unroll
      for (int tm = 0; tm < 2; ++tm) {
#pragma unroll
        for (int r = 0; r < 4; ++r) {
          const int row = row0 + wr + tm * 16 + quad * 4 + r;
          C[(size_t)row * FC_N + col] = acc[tm][tn][r] + bv;
        }
      }
    }
  }
}

// ---------------- Kuramoto: one block (512 threads) per batch, 25 steps ----------------
__global__ __launch_bounds__(512) void kuramoto_kernel(
    const float* __restrict__ ph0, const int* __restrict__ conn,
    const float* __restrict__ cpl, float* __restrict__ out) {
  __shared__ float ph[NPOS];
  __shared__ float2 sc[NPOS];
  const int b = blockIdx.x, tid = threadIdx.x;
  int rj[3][8];
  float rc[3][8];
#pragma unroll
  for (int s = 0; s < 3; ++s) {
    const int i = tid + s * 512;
    if (i < NPOS) {
      const float p = ph0[(size_t)b * NPOS + i];
      ph[i] = p;
      out[(size_t)b * NPOS + i] = p;  // step 0 = initial phase
      const size_t base = (size_t)b * (NPOS * 8) + (size_t)i * 8;
      const int4 j0 = *(const int4*)(conn + base);
      const int4 j1 = *(const int4*)(conn + base + 4);
      const float4 c0 = *(const float4*)(cpl + base);
      const float4 c1 = *(const float4*)(cpl + base + 4);
      rj[s][0] = j0.x; rj[s][1] = j0.y; rj[s][2] = j0.z; rj[s][3] = j0.w;
      rj[s][4] = j1.x; rj[s][5] = j1.y; rj[s][6] = j1.z; rj[s][7] = j1.w;
      rc[s][0] = c0.x; rc[s][1] = c0.y; rc[s][2] = c0.z; rc[s][3] = c0.w;
      rc[s][4] = c1.x; rc[s][5] = c1.y; rc[s][6] = c1.z; rc[s][7] = c1.w;
    } else {
#pragma unroll
      for (int k = 0; k < 8; ++k) { rj[s][k] = 0; rc[s][k] = 0.f; }
    }
  }
  float ep = 0.1f;
  for (int t = 0; t < STEPS; ++t) {
    __syncthreads();
    for (int i = tid; i < NPOS; i += 512) {
      float s, c;
      __sincosf(ph[i], &s, &c);
      sc[i] = make_float2(s, c);
    }
    __syncthreads();
    float* op = out + (size_t)(t + 1) * PH_STRIDE + (size_t)b * NPOS;
#pragma unroll
    for (int s = 0; s < 3; ++s) {
      const int i = tid + s * 512;
      if (i < NPOS) {
        float ss = 0.f, cs = 0.f;
#pragma unroll
        for (int k = 0; k < 8; ++k) {
          const float2 v = sc[rj[s][k]];
          ss = fmaf(rc[s][k], v.x, ss);
          cs = fmaf(rc[s][k], v.y, cs);
        }
        const float2 me = sc[i];
        const float np = ph[i] + ep * (me.y * ss - me.x * cs);
        ph[i] = np;
        op[i] = np;
      }
    }
    ep = ep * (1.0f - 0.02f * (float)t);  // ep -= 0.5*t*ep/25
  }
}

extern "C" void kernel_launch(void* const* d_in, const int* in_sizes, int n_in,
                              void* d_out, int out_size, void* d_ws, size_t ws_size,
                              hipStream_t stream) {
  const float* input = (const float*)d_in[0];
  const float* ph0   = (const float*)d_in[1];
  const int*   conn  = (const int*)d_in[2];
  // d_in[3] = episodes (always 25)
  const float* w1 = (const float*)d_in[4];
  const float* b1 = (const float*)d_in[5];
  const float* w2 = (const float*)d_in[6];
  const float* b2 = (const float*)d_in[7];
  const float* w3 = (const float*)d_in[8];
  const float* b3 = (const float*)d_in[9];
  const float* fcw = (const float*)d_in[10];
  const float* fcb = (const float*)d_in[11];
  float* out = (float*)d_out;

  // workspace layout (bytes):
  // Abuf bf16 [0, 42467328) | Wbuf bf16 [42467328, 48660480) | w1t f32 [.., +288)
  // w2t bf16 [48660768, +3072) | w3t bf16 [48663840, +10240)
  ushort* Abuf = (ushort*)d_ws;
  ushort* Wbuf = (ushort*)((char*)d_ws + 42467328);
  float*  w1t  = (float*)((char*)d_ws + 48660480);
  ushort* w2t  = (ushort*)((char*)d_ws + 48660768);
  ushort* w3t  = (ushort*)((char*)d_ws + 48663840);
  float* fcout = out + PH_TOTAL;

  wprep_kernel<<<1, 256, 0, stream>>>(w1, w2, w3, w1t, w2t, w3t);
  wcvt_kernel<<<(FC_NPAD * FC_K) / 256, 256, 0, stream>>>(fcw, Wbuf);
  conv_fused_kernel<<<dim3(BATCH, 3), 256, 0, stream>>>(input, w1t, b1, w2t, b2, w3t, b3, Abuf);
  gemm_kernel<<<dim3(FC_NPAD / 128, FC_M / 64), 256, 0, stream>>>(Abuf, Wbuf, fcb, fcout);
  kuramoto_kernel<<<BATCH, 512, 0, stream>>>(ph0, conn, fcout, out);
}

// Round 4
// 270.968 us; speedup vs baseline: 3.1006x; 1.0588x over previous
//
#include <hip/hip_runtime.h>
#include <hip/hip_bf16.h>

#define NPOS 1296              // 36*36 oscillators
#define BATCH 512
#define STEPS 25
#define PH_STRIDE (BATCH * NPOS)            // 663552
#define PH_TOTAL ((STEPS + 1) * PH_STRIDE)  // 17252352
#define FC_K 3456
#define FC_N 864
#define FC_NPAD 896
#define FC_M 6144

typedef float f32x4 __attribute__((ext_vector_type(4)));
typedef __bf16 bf16x8 __attribute__((ext_vector_type(8)));

__device__ __forceinline__ ushort f2bf(float f) {
  union { float f; unsigned u; } v; v.f = f;
  unsigned r = v.u + 0x7FFFu + ((v.u >> 16) & 1u);  // RNE
  return (ushort)(r >> 16);
}
__device__ __forceinline__ float bf2f(ushort h) {
  union { unsigned u; float f; } v; v.u = ((unsigned)h) << 16; return v.f;
}

__device__ __forceinline__ void async_copy16(void* lds, const void* g) {
  __builtin_amdgcn_global_load_lds(
      (const __attribute__((address_space(1))) unsigned*)g,
      (__attribute__((address_space(3))) unsigned*)lds, 16, 0, 0);
}

// ---------------- weight prep: transpose to MFMA-friendly [co][k] layouts ----------------
__global__ __launch_bounds__(256) void wprep_kernel(
    const float* __restrict__ w1, const float* __restrict__ w2, const float* __restrict__ w3,
    float* __restrict__ w1t, ushort* __restrict__ w2t, ushort* __restrict__ w3t) {
  const int tid = threadIdx.x;
  for (int i = tid; i < 72; i += 256) {
    const int s = i / 8, co = i - s * 8;
    w1t[i] = w1[co * 9 + s];
  }
  for (int i = tid; i < 16 * 96; i += 256) {
    const int co = i / 96, k = i - co * 96;
    const int s = k / 8, ci = k - s * 8;
    w2t[i] = (k < 72) ? f2bf(w2[(co * 8 + ci) * 9 + s]) : (ushort)0;
  }
  for (int i = tid; i < 32 * 160; i += 256) {
    const int co = i / 160, k = i - co * 160;
    const int s = k / 16, ci = k - s * 16;
    w3t[i] = (k < 144) ? f2bf(w3[(co * 16 + ci) * 9 + s]) : (ushort)0;
  }
}

// ---------------- fused conv1(VALU) + conv2(MFMA) + conv3(MFMA+sigmoid) ----------------
__global__ __launch_bounds__(256, 4) void conv_fused_kernel(
    const float* __restrict__ in, const float* __restrict__ w1t, const float* __restrict__ b1,
    const ushort* __restrict__ w2t, const float* __restrict__ b2,
    const ushort* __restrict__ w3t, const float* __restrict__ b3,
    ushort* __restrict__ aout) {
  __shared__ __align__(16) float sIn[18][40];          // input rows r0-3..r0+14, col x at x+2
  __shared__ __align__(16) ushort sC1[18][40][8];      // c1 rows r0-2..r0+13 (rows 16,17 zero)
  __shared__ __align__(16) ushort sC2[16][40][16];     // c2 rows r0-1..r0+12 (rows 14,15 zero)
  const int b = blockIdx.x, band = blockIdx.y, tid = threadIdx.x;
  const int r0 = band * 12;
  const int wave = tid >> 6, lane = tid & 63;
  const int quad = lane >> 4, l16 = lane & 15;
  {
    const uint4 zz = make_uint4(0, 0, 0, 0);
    for (int i = tid; i < 180; i += 256) ((uint4*)sIn)[i] = zz;
    for (int i = tid; i < 720; i += 256) ((uint4*)sC1)[i] = zz;
    for (int i = tid; i < 1280; i += 256) ((uint4*)sC2)[i] = zz;
  }
  __syncthreads();
  for (int i = tid; i < 18 * 18; i += 256) {
    const int r = i / 18, c = i - r * 18;
    const int gy = r0 - 3 + r;
    if ((unsigned)gy < 36u)
      *(float2*)&sIn[r][2 + 2 * c] = *(const float2*)(in + (size_t)b * NPOS + gy * 36 + 2 * c);
  }
  __syncthreads();
  // conv1
  for (int i = tid; i < 16 * 36; i += 256) {
    const int lr = i / 36, x = i - lr * 36;
    float acc[8];
#pragma unroll
    for (int co = 0; co < 8; ++co) acc[co] = b1[co];
#pragma unroll
    for (int s = 0; s < 9; ++s) {
      const int dy = s / 3, dx = s - 3 * dy;
      const float v = sIn[lr + dy][x + 1 + dx];
#pragma unroll
      for (int co = 0; co < 8; ++co) acc[co] = fmaf(w1t[s * 8 + co], v, acc[co]);
    }
    const int g1 = r0 - 2 + lr;
    if ((unsigned)g1 < 36u) {
      uint4 pk;
      pk.x = (uint)f2bf(fmaxf(acc[0], 0.f)) | ((uint)f2bf(fmaxf(acc[1], 0.f)) << 16);
      pk.y = (uint)f2bf(fmaxf(acc[2], 0.f)) | ((uint)f2bf(fmaxf(acc[3], 0.f)) << 16);
      pk.z = (uint)f2bf(fmaxf(acc[4], 0.f)) | ((uint)f2bf(fmaxf(acc[5], 0.f)) << 16);
      pk.w = (uint)f2bf(fmaxf(acc[6], 0.f)) | ((uint)f2bf(fmaxf(acc[7], 0.f)) << 16);
      *(uint4*)&sC1[lr][x + 2][0] = pk;
    }
  }
  __syncthreads();
  // conv2 via MFMA: M=512 px, N=16 co, K=96 (72 real)
  bf16x8 w2f[3];
#pragma unroll
  for (int f = 0; f < 3; ++f)
    w2f[f] = *(const bf16x8*)(w2t + l16 * 96 + f * 32 + quad * 8);
  const float bias2 = b2[l16];
  for (int chunk = wave; chunk < 32; chunk += 4) {
    const int m = chunk * 16 + l16;
    const int oy = m / 36, x = m - oy * 36;
    f32x4 acc = {0.f, 0.f, 0.f, 0.f};
#pragma unroll
    for (int f = 0; f < 3; ++f) {
      const int s0 = 4 * f + quad;
      const int dy = s0 / 3, dx = s0 - 3 * dy;
      const bf16x8 af = *(const bf16x8*)&sC1[oy + dy][x + 1 + dx][0];
      acc = __builtin_amdgcn_mfma_f32_16x16x32_bf16(af, w2f[f], acc, 0, 0, 0);
    }
#pragma unroll
    for (int r = 0; r < 4; ++r) {
      const int px = chunk * 16 + quad * 4 + r;
      const int oy2 = px / 36, x2 = px - oy2 * 36;
      const int g2 = r0 - 1 + oy2;
      if (px < 504 && (unsigned)g2 < 36u)
        sC2[oy2][x2 + 2][l16] = f2bf(fmaxf(acc[r] + bias2, 0.f));
    }
  }
  __syncthreads();
  // conv3 via MFMA: M=432 px, N=32 co (2 tiles), K=160 (144 real)
  bf16x8 w3f[2][5];
#pragma unroll
  for (int t = 0; t < 2; ++t)
#pragma unroll
    for (int f = 0; f < 5; ++f)
      w3f[t][f] = *(const bf16x8*)(w3t + (t * 16 + l16) * 160 + f * 32 + quad * 8);
  const float bias3a = b3[l16], bias3b = b3[16 + l16];
  ushort* ob = aout + (size_t)b * (32 * NPOS) + r0 * 36;
  for (int chunk = wave; chunk < 27; chunk += 4) {
    const int m = chunk * 16 + l16;
    const int oy = m / 36, x = m - oy * 36;
    f32x4 acc0 = {0.f, 0.f, 0.f, 0.f}, acc1 = {0.f, 0.f, 0.f, 0.f};
#pragma unroll
    for (int f = 0; f < 5; ++f) {
      const int s0 = 2 * f + (quad >> 1);
      const int dy = s0 / 3, dx = s0 - 3 * dy;
      const bf16x8 af = *(const bf16x8*)&sC2[oy + dy][x + 1 + dx][(quad & 1) * 8];
      acc0 = __builtin_amdgcn_mfma_f32_16x16x32_bf16(af, w3f[0][f], acc0, 0, 0, 0);
      acc1 = __builtin_amdgcn_mfma_f32_16x16x32_bf16(af, w3f[1][f], acc1, 0, 0, 0);
    }
    const int pxb = chunk * 16 + quad * 4;
    ushort4 pk;
#pragma unroll
    for (int r = 0; r < 4; ++r)
      ((ushort*)&pk)[r] = f2bf(1.f / (1.f + __expf(-(acc0[r] + bias3a))));
    *(ushort4*)(ob + (size_t)l16 * NPOS + pxb) = pk;
#pragma unroll
    for (int r = 0; r < 4; ++r)
      ((ushort*)&pk)[r] = f2bf(1.f / (1.f + __expf(-(acc1[r] + bias3b))));
    *(ushort4*)(ob + (size_t)(16 + l16) * NPOS + pxb) = pk;
  }
}

// ---------------- fc_w (864x3456 f32) -> bf16, rows padded to 896 with zeros ----------------
__global__ __launch_bounds__(256) void wcvt_kernel(const float* __restrict__ w, ushort* __restrict__ wb) {
  const int idx = blockIdx.x * 256 + threadIdx.x;
  if (idx >= FC_NPAD * FC_K) return;
  const int n = idx / FC_K;
  wb[idx] = (n < FC_N) ? f2bf(w[idx]) : (ushort)0;
}

// ---------------- bf16 NT GEMM: C[m][n] = sum_k A[m][k]*Bt[n][k] + bias[n] ----------------
// 64x128 tile, BK=64 as two 32-slabs (6 async copies + 16 MFMA per barrier-pair).
// 1D grid 672, XCD-swizzled: all 7 N-tiles of one A-strip land on one XCD's L2.
__global__ __launch_bounds__(256) void gemm_kernel(
    const ushort* __restrict__ A, const ushort* __restrict__ Bt,
    const float* __restrict__ bias, float* __restrict__ C) {
  __shared__ __align__(16) ushort sA[2][64 * 32];
  __shared__ __align__(16) ushort sB[2][128 * 32];
  const int tid = threadIdx.x;
  const int lin = blockIdx.x;
  const int xcd = lin & 7, idx = lin >> 3;         // 672 blocks: xcd 0..7, idx 0..83
  const int bm = xcd + 8 * (idx / 7);              // m-band 0..95, fixed mod-8 class per XCD
  const int bn = idx % 7;
  const int row0 = bm * 64, col0 = bn * 128;
  const int wave = tid >> 6, lane = tid & 63;
  const int wr = (wave >> 1) * 32, wc = (wave & 1) * 64;
  const int quad = lane >> 4, l16 = lane & 15;
  const int srow = tid >> 2;       // 0..63
  const int skk = (tid & 3) * 8;
  f32x4 acc[2][4] = {};
  const ushort* Abase = A + ((size_t)row0 + srow) * FC_K + skk;
  const ushort* Bbase = Bt + ((size_t)col0 + srow) * FC_K + skk;
  ushort* sA0 = sA[0] + wave * 512;  // wave-uniform base; + lane*16B == tid*8 ushorts
  ushort* sA1 = sA[1] + wave * 512;
  ushort* sB0 = sB[0] + wave * 512;
  ushort* sB1 = sB[1] + wave * 512;
  for (int kt = 0; kt < FC_K / 64; ++kt) {
    const int k0 = kt * 64;
    __syncthreads();
    async_copy16(sA0, Abase + k0);
    async_copy16(sB0, Bbase + k0);
    async_copy16(sB0 + 2048, Bbase + (size_t)64 * FC_K + k0);
    async_copy16(sA1, Abase + k0 + 32);
    async_copy16(sB1, Bbase + k0 + 32);
    async_copy16(sB1 + 2048, Bbase + (size_t)64 * FC_K + k0 + 32);
    __syncthreads();
#pragma unroll
    for (int s = 0; s < 2; ++s) {
      bf16x8 af[2], bfr[4];
#pragma unroll
      for (int t = 0; t < 2; ++t)
        af[t] = *(const bf16x8*)(sA[s] + (wr + t * 16 + l16) * 32 + quad * 8);
#pragma unroll
      for (int t = 0; t < 4; ++t)
        bfr[t] = *(const bf16x8*)(sB[s] + (wc + t * 16 + l16) * 32 + quad * 8);
#pragma unroll
      for (int tm = 0; tm < 2; ++tm)
#pragma unroll
        for (int tn = 0; tn < 4; ++tn)
          acc[tm][tn] = __builtin_amdgcn_mfma_f32_16x16x32_bf16(af[tm], bfr[tn], acc[tm][tn], 0, 0, 0);
    }
  }
#pragma unroll
  for (int tn = 0; tn < 4; ++tn) {
    const int col = col0 + wc + tn * 16 + l16;
    if (col < FC_N) {
      const float bv = bias[col];
#pragma unroll
      for (int tm = 0; tm < 2; ++tm) {
#pragma unroll
        for (int r = 0; r < 4; ++r) {
          const int row = row0 + wr + tm * 16 + quad * 4 + r;
          C[(size_t)row * FC_N + col] = acc[tm][tn][r] + bv;
        }
      }
    }
  }
}

// ---------------- Kuramoto: one block (512 threads) per batch, 25 steps ----------------
__global__ __launch_bounds__(512) void kuramoto_kernel(
    const float* __restrict__ ph0, const int* __restrict__ conn,
    const float* __restrict__ cpl, float* __restrict__ out) {
  __shared__ float ph[NPOS];
  __shared__ float2 sc[NPOS];
  const int b = blockIdx.x, tid = threadIdx.x;
  int rj[3][8];
  float rc[3][8];
#pragma unroll
  for (int s = 0; s < 3; ++s) {
    const int i = tid + s * 512;
    if (i < NPOS) {
      const float p = ph0[(size_t)b * NPOS + i];
      ph[i] = p;
      __builtin_nontemporal_store(p, out + (size_t)b * NPOS + i);  // step 0
      const size_t base = (size_t)b * (NPOS * 8) + (size_t)i * 8;
      const int4 j0 = *(const int4*)(conn + base);
      const int4 j1 = *(const int4*)(conn + base + 4);
      const float4 c0 = *(const float4*)(cpl + base);
      const float4 c1 = *(const float4*)(cpl + base + 4);
      rj[s][0] = j0.x; rj[s][1] = j0.y; rj[s][2] = j0.z; rj[s][3] = j0.w;
      rj[s][4] = j1.x; rj[s][5] = j1.y; rj[s][6] = j1.z; rj[s][7] = j1.w;
      rc[s][0] = c0.x; rc[s][1] = c0.y; rc[s][2] = c0.z; rc[s][3] = c0.w;
      rc[s][4] = c1.x; rc[s][5] = c1.y; rc[s][6] = c1.z; rc[s][7] = c1.w;
    } else {
#pragma unroll
      for (int k = 0; k < 8; ++k) { rj[s][k] = 0; rc[s][k] = 0.f; }
    }
  }
  float ep = 0.1f;
  for (int t = 0; t < STEPS; ++t) {
    __syncthreads();
    for (int i = tid; i < NPOS; i += 512) {
      float s, c;
      __sincosf(ph[i], &s, &c);
      sc[i] = make_float2(s, c);
    }
    __syncthreads();
    float* op = out + (size_t)(t + 1) * PH_STRIDE + (size_t)b * NPOS;
#pragma unroll
    for (int s = 0; s < 3; ++s) {
      const int i = tid + s * 512;
      if (i < NPOS) {
        float ss = 0.f, cs = 0.f;
#pragma unroll
        for (int k = 0; k < 8; ++k) {
          const float2 v = sc[rj[s][k]];
          ss = fmaf(rc[s][k], v.x, ss);
          cs = fmaf(rc[s][k], v.y, cs);
        }
        const float2 me = sc[i];
        const float np = ph[i] + ep * (me.y * ss - me.x * cs);
        ph[i] = np;
        __builtin_nontemporal_store(np, op + i);
      }
    }
    ep = ep * (1.0f - 0.02f * (float)t);  // ep -= 0.5*t*ep/25
  }
}

extern "C" void kernel_launch(void* const* d_in, const int* in_sizes, int n_in,
                              void* d_out, int out_size, void* d_ws, size_t ws_size,
                              hipStream_t stream) {
  const float* input = (const float*)d_in[0];
  const float* ph0   = (const float*)d_in[1];
  const int*   conn  = (const int*)d_in[2];
  // d_in[3] = episodes (always 25)
  const float* w1 = (const float*)d_in[4];
  const float* b1 = (const float*)d_in[5];
  const float* w2 = (const float*)d_in[6];
  const float* b2 = (const float*)d_in[7];
  const float* w3 = (const float*)d_in[8];
  const float* b3 = (const float*)d_in[9];
  const float* fcw = (const float*)d_in[10];
  const float* fcb = (const float*)d_in[11];
  float* out = (float*)d_out;

  // workspace layout (bytes):
  // Abuf bf16 [0, 42467328) | Wbuf bf16 [42467328, 48660480) | w1t f32 [.., +288)
  // w2t bf16 [48660768, +3072) | w3t bf16 [48663840, +10240)
  ushort* Abuf = (ushort*)d_ws;
  ushort* Wbuf = (ushort*)((char*)d_ws + 42467328);
  float*  w1t  = (float*)((char*)d_ws + 48660480);
  ushort* w2t  = (ushort*)((char*)d_ws + 48660768);
  ushort* w3t  = (ushort*)((char*)d_ws + 48663840);
  float* fcout = out + PH_TOTAL;

  wprep_kernel<<<1, 256, 0, stream>>>(w1, w2, w3, w1t, w2t, w3t);
  wcvt_kernel<<<(FC_NPAD * FC_K) / 256, 256, 0, stream>>>(fcw, Wbuf);
  conv_fused_kernel<<<dim3(BATCH, 3), 256, 0, stream>>>(input, w1t, b1, w2t, b2, w3t, b3, Abuf);
  gemm_kernel<<<672, 256, 0, stream>>>(Abuf, Wbuf, fcb, fcout);
  kuramoto_kernel<<<BATCH, 512, 0, stream>>>(ph0, conn, fcout, out);
}

// Round 5
// 268.848 us; speedup vs baseline: 3.1250x; 1.0079x over previous
//
#include <hip/hip_runtime.h>
#include <hip/hip_bf16.h>

#define NPOS 1296              // 36*36 oscillators
#define BATCH 512
#define STEPS 25
#define PH_STRIDE (BATCH * NPOS)            // 663552
#define PH_TOTAL ((STEPS + 1) * PH_STRIDE)  // 17252352
#define FC_K 3456
#define FC_N 864
#define FC_NPAD 896
#define FC_M 6144

typedef float f32x4 __attribute__((ext_vector_type(4)));
typedef __bf16 bf16x8 __attribute__((ext_vector_type(8)));

__device__ __forceinline__ ushort f2bf(float f) {
  union { float f; unsigned u; } v; v.f = f;
  unsigned r = v.u + 0x7FFFu + ((v.u >> 16) & 1u);  // RNE
  return (ushort)(r >> 16);
}
__device__ __forceinline__ float bf2f(ushort h) {
  union { unsigned u; float f; } v; v.u = ((unsigned)h) << 16; return v.f;
}

__device__ __forceinline__ void async_copy16(void* lds, const void* g) {
  __builtin_amdgcn_global_load_lds(
      (const __attribute__((address_space(1))) unsigned*)g,
      (__attribute__((address_space(3))) unsigned*)lds, 16, 0, 0);
}

// ---------------- weight prep: transpose to MFMA-friendly [co][k] layouts ----------------
__global__ __launch_bounds__(256) void wprep_kernel(
    const float* __restrict__ w1, const float* __restrict__ w2, const float* __restrict__ w3,
    float* __restrict__ w1t, ushort* __restrict__ w2t, ushort* __restrict__ w3t) {
  const int tid = threadIdx.x;
  for (int i = tid; i < 72; i += 256) {
    const int s = i / 8, co = i - s * 8;
    w1t[i] = w1[co * 9 + s];
  }
  for (int i = tid; i < 16 * 96; i += 256) {
    const int co = i / 96, k = i - co * 96;
    const int s = k / 8, ci = k - s * 8;
    w2t[i] = (k < 72) ? f2bf(w2[(co * 8 + ci) * 9 + s]) : (ushort)0;
  }
  for (int i = tid; i < 32 * 160; i += 256) {
    const int co = i / 160, k = i - co * 160;
    const int s = k / 16, ci = k - s * 16;
    w3t[i] = (k < 144) ? f2bf(w3[(co * 16 + ci) * 9 + s]) : (ushort)0;
  }
}

// ---------------- fused conv1(VALU) + conv2(MFMA) + conv3(MFMA+sigmoid) ----------------
__global__ __launch_bounds__(256, 4) void conv_fused_kernel(
    const float* __restrict__ in, const float* __restrict__ w1t, const float* __restrict__ b1,
    const ushort* __restrict__ w2t, const float* __restrict__ b2,
    const ushort* __restrict__ w3t, const float* __restrict__ b3,
    ushort* __restrict__ aout) {
  __shared__ __align__(16) float sIn[18][40];          // input rows r0-3..r0+14, col x at x+2
  __shared__ __align__(16) ushort sC1[18][40][8];      // c1 rows r0-2..r0+13 (rows 16,17 zero)
  __shared__ __align__(16) ushort sC2[16][40][16];     // c2 rows r0-1..r0+12 (rows 14,15 zero)
  const int b = blockIdx.x, band = blockIdx.y, tid = threadIdx.x;
  const int r0 = band * 12;
  const int wave = tid >> 6, lane = tid & 63;
  const int quad = lane >> 4, l16 = lane & 15;
  {
    const uint4 zz = make_uint4(0, 0, 0, 0);
    for (int i = tid; i < 180; i += 256) ((uint4*)sIn)[i] = zz;
    for (int i = tid; i < 720; i += 256) ((uint4*)sC1)[i] = zz;
    for (int i = tid; i < 1280; i += 256) ((uint4*)sC2)[i] = zz;
  }
  __syncthreads();
  for (int i = tid; i < 18 * 18; i += 256) {
    const int r = i / 18, c = i - r * 18;
    const int gy = r0 - 3 + r;
    if ((unsigned)gy < 36u)
      *(float2*)&sIn[r][2 + 2 * c] = *(const float2*)(in + (size_t)b * NPOS + gy * 36 + 2 * c);
  }
  __syncthreads();
  // conv1
  for (int i = tid; i < 16 * 36; i += 256) {
    const int lr = i / 36, x = i - lr * 36;
    float acc[8];
#pragma unroll
    for (int co = 0; co < 8; ++co) acc[co] = b1[co];
#pragma unroll
    for (int s = 0; s < 9; ++s) {
      const int dy = s / 3, dx = s - 3 * dy;
      const float v = sIn[lr + dy][x + 1 + dx];
#pragma unroll
      for (int co = 0; co < 8; ++co) acc[co] = fmaf(w1t[s * 8 + co], v, acc[co]);
    }
    const int g1 = r0 - 2 + lr;
    if ((unsigned)g1 < 36u) {
      uint4 pk;
      pk.x = (uint)f2bf(fmaxf(acc[0], 0.f)) | ((uint)f2bf(fmaxf(acc[1], 0.f)) << 16);
      pk.y = (uint)f2bf(fmaxf(acc[2], 0.f)) | ((uint)f2bf(fmaxf(acc[3], 0.f)) << 16);
      pk.z = (uint)f2bf(fmaxf(acc[4], 0.f)) | ((uint)f2bf(fmaxf(acc[5], 0.f)) << 16);
      pk.w = (uint)f2bf(fmaxf(acc[6], 0.f)) | ((uint)f2bf(fmaxf(acc[7], 0.f)) << 16);
      *(uint4*)&sC1[lr][x + 2][0] = pk;
    }
  }
  __syncthreads();
  // conv2 via MFMA: M=512 px, N=16 co, K=96 (72 real)
  bf16x8 w2f[3];
#pragma unroll
  for (int f = 0; f < 3; ++f)
    w2f[f] = *(const bf16x8*)(w2t + l16 * 96 + f * 32 + quad * 8);
  const float bias2 = b2[l16];
  for (int chunk = wave; chunk < 32; chunk += 4) {
    const int m = chunk * 16 + l16;
    const int oy = m / 36, x = m - oy * 36;
    f32x4 acc = {0.f, 0.f, 0.f, 0.f};
#pragma unroll
    for (int f = 0; f < 3; ++f) {
      const int s0 = 4 * f + quad;
      const int dy = s0 / 3, dx = s0 - 3 * dy;
      const bf16x8 af = *(const bf16x8*)&sC1[oy + dy][x + 1 + dx][0];
      acc = __builtin_amdgcn_mfma_f32_16x16x32_bf16(af, w2f[f], acc, 0, 0, 0);
    }
#pragma unroll
    for (int r = 0; r < 4; ++r) {
      const int px = chunk * 16 + quad * 4 + r;
      const int oy2 = px / 36, x2 = px - oy2 * 36;
      const int g2 = r0 - 1 + oy2;
      if (px < 504 && (unsigned)g2 < 36u)
        sC2[oy2][x2 + 2][l16] = f2bf(fmaxf(acc[r] + bias2, 0.f));
    }
  }
  __syncthreads();
  // conv3 via MFMA: M=432 px, N=32 co (2 tiles), K=160 (144 real)
  bf16x8 w3f[2][5];
#pragma unroll
  for (int t = 0; t < 2; ++t)
#pragma unroll
    for (int f = 0; f < 5; ++f)
      w3f[t][f] = *(const bf16x8*)(w3t + (t * 16 + l16) * 160 + f * 32 + quad * 8);
  const float bias3a = b3[l16], bias3b = b3[16 + l16];
  ushort* ob = aout + (size_t)b * (32 * NPOS) + r0 * 36;
  for (int chunk = wave; chunk < 27; chunk += 4) {
    const int m = chunk * 16 + l16;
    const int oy = m / 36, x = m - oy * 36;
    f32x4 acc0 = {0.f, 0.f, 0.f, 0.f}, acc1 = {0.f, 0.f, 0.f, 0.f};
#pragma unroll
    for (int f = 0; f < 5; ++f) {
      const int s0 = 2 * f + (quad >> 1);
      const int dy = s0 / 3, dx = s0 - 3 * dy;
      const bf16x8 af = *(const bf16x8*)&sC2[oy + dy][x + 1 + dx][(quad & 1) * 8];
      acc0 = __builtin_amdgcn_mfma_f32_16x16x32_bf16(af, w3f[0][f], acc0, 0, 0, 0);
      acc1 = __builtin_amdgcn_mfma_f32_16x16x32_bf16(af, w3f[1][f], acc1, 0, 0, 0);
    }
    const int pxb = chunk * 16 + quad * 4;
    ushort4 pk;
#pragma unroll
    for (int r = 0; r < 4; ++r)
      ((ushort*)&pk)[r] = f2bf(1.f / (1.f + __expf(-(acc0[r] + bias3a))));
    *(ushort4*)(ob + (size_t)l16 * NPOS + pxb) = pk;
#pragma unroll
    for (int r = 0; r < 4; ++r)
      ((ushort*)&pk)[r] = f2bf(1.f / (1.f + __expf(-(acc1[r] + bias3b))));
    *(ushort4*)(ob + (size_t)(16 + l16) * NPOS + pxb) = pk;
  }
}

// ---------------- fc_w (864x3456 f32) -> bf16, rows padded to 896 with zeros ----------------
__global__ __launch_bounds__(256) void wcvt_kernel(const float* __restrict__ w, ushort* __restrict__ wb) {
  const int idx = blockIdx.x * 256 + threadIdx.x;
  if (idx >= FC_NPAD * FC_K) return;
  const int n = idx / FC_K;
  wb[idx] = (n < FC_N) ? f2bf(w[idx]) : (ushort)0;
}

// ---------------- bf16 NT GEMM: C[m][n] = sum_k A[m][k]*Bt[n][k] + bias[n] ----------------
// 96x128 block tile, 4 waves of 48x64 (3x4 acc -> 24 MFMA per barrier-pair), BK=64 as two
// 32-slabs staged via global_load_lds. Grid 448 (1.75/CU), XCD-swizzled so all 7 N-tiles of
// an A-strip share one XCD's L2.
__global__ __launch_bounds__(256) void gemm_kernel(
    const ushort* __restrict__ A, const ushort* __restrict__ Bt,
    const float* __restrict__ bias, float* __restrict__ C) {
  __shared__ __align__(16) ushort sA[2][96 * 32];
  __shared__ __align__(16) ushort sB[2][128 * 32];
  const int tid = threadIdx.x;
  const int lin = blockIdx.x;
  const int xcd = lin & 7, g = lin >> 3;           // 448 blocks: g 0..55
  const int bn = g % 7;
  const int bm = xcd + 8 * (g / 7);                // 0..63
  const int row0 = bm * 96, col0 = bn * 128;
  const int wave = tid >> 6, lane = tid & 63;
  const int wr = (wave >> 1) * 48, wc = (wave & 1) * 64;
  const int quad = lane >> 4, l16 = lane & 15;
  f32x4 acc[3][4] = {};
  // staging sources: thread t covers chunk row (t>>2), k-octet (t&3)
  const ushort* Asrc  = A  + ((size_t)row0 + (tid >> 2)) * FC_K + (tid & 3) * 8;
  const ushort* Asrc2 = Asrc + (size_t)64 * FC_K;   // rows 64..95 (tid<128 only)
  const ushort* Bsrc  = Bt + ((size_t)col0 + (tid >> 2)) * FC_K + (tid & 3) * 8;
  const ushort* Bsrc2 = Bsrc + (size_t)64 * FC_K;   // rows 64..127
  const int halfwave = (tid < 128);                 // wave-uniform
  for (int kt = 0; kt < FC_K / 64; ++kt) {
    const int k0 = kt * 64;
    __syncthreads();
#pragma unroll
    for (int s = 0; s < 2; ++s) {
      const int off = k0 + s * 32;
      async_copy16(sA[s] + wave * 512, Asrc + off);
      async_copy16(sB[s] + wave * 512, Bsrc + off);
      async_copy16(sB[s] + 2048 + wave * 512, Bsrc2 + off);
      if (halfwave) async_copy16(sA[s] + 2048 + wave * 512, Asrc2 + off);
    }
    __syncthreads();
#pragma unroll
    for (int s = 0; s < 2; ++s) {
      bf16x8 af[3], bfr[4];
#pragma unroll
      for (int t = 0; t < 3; ++t)
        af[t] = *(const bf16x8*)(sA[s] + (wr + t * 16 + l16) * 32 + quad * 8);
#pragma unroll
      for (int t = 0; t < 4; ++t)
        bfr[t] = *(const bf16x8*)(sB[s] + (wc + t * 16 + l16) * 32 + quad * 8);
#pragma unroll
      for (int tm = 0; tm < 3; ++tm)
#pragma unroll
        for (int tn = 0; tn < 4; ++tn)
          acc[tm][tn] = __builtin_amdgcn_mfma_f32_16x16x32_bf16(af[tm], bfr[tn], acc[tm][tn], 0, 0, 0);
    }
  }
#pragma unroll
  for (int tn = 0; tn < 4; ++tn) {
    const int col = col0 + wc + tn * 16 + l16;
    if (col < FC_N) {
      const float bv = bias[col];
#pragma unroll
      for (int tm = 0; tm < 3; ++tm) {
#pragma unroll
        for (int r = 0; r < 4; ++r) {
          const int row = row0 + wr + tm * 16 + quad * 4 + r;
          C[(size_t)row * FC_N + col] = acc[tm][tn][r] + bv;
        }
      }
    }
  }
}

// ---------------- Kuramoto: one block (512 threads) per batch, 25 steps ----------------
__global__ __launch_bounds__(512) void kuramoto_kernel(
    const float* __restrict__ ph0, const int* __restrict__ conn,
    const float* __restrict__ cpl, float* __restrict__ out) {
  __shared__ float ph[NPOS];
  __shared__ float2 sc[NPOS];
  const int b = blockIdx.x, tid = threadIdx.x;
  int rj[3][8];
  float rc[3][8];
#pragma unroll
  for (int s = 0; s < 3; ++s) {
    const int i = tid + s * 512;
    if (i < NPOS) {
      const float p = ph0[(size_t)b * NPOS + i];
      ph[i] = p;
      __builtin_nontemporal_store(p, out + (size_t)b * NPOS + i);  // step 0
      const size_t base = (size_t)b * (NPOS * 8) + (size_t)i * 8;
      const int4 j0 = *(const int4*)(conn + base);
      const int4 j1 = *(const int4*)(conn + base + 4);
      const float4 c0 = *(const float4*)(cpl + base);
      const float4 c1 = *(const float4*)(cpl + base + 4);
      rj[s][0] = j0.x; rj[s][1] = j0.y; rj[s][2] = j0.z; rj[s][3] = j0.w;
      rj[s][4] = j1.x; rj[s][5] = j1.y; rj[s][6] = j1.z; rj[s][7] = j1.w;
      rc[s][0] = c0.x; rc[s][1] = c0.y; rc[s][2] = c0.z; rc[s][3] = c0.w;
      rc[s][4] = c1.x; rc[s][5] = c1.y; rc[s][6] = c1.z; rc[s][7] = c1.w;
    } else {
#pragma unroll
      for (int k = 0; k < 8; ++k) { rj[s][k] = 0; rc[s][k] = 0.f; }
    }
  }
  float ep = 0.1f;
  for (int t = 0; t < STEPS; ++t) {
    __syncthreads();
    for (int i = tid; i < NPOS; i += 512) {
      float s, c;
      __sincosf(ph[i], &s, &c);
      sc[i] = make_float2(s, c);
    }
    __syncthreads();
    float* op = out + (size_t)(t + 1) * PH_STRIDE + (size_t)b * NPOS;
#pragma unroll
    for (int s = 0; s < 3; ++s) {
      const int i = tid + s * 512;
      if (i < NPOS) {
        float ss = 0.f, cs = 0.f;
#pragma unroll
        for (int k = 0; k < 8; ++k) {
          const float2 v = sc[rj[s][k]];
          ss = fmaf(rc[s][k], v.x, ss);
          cs = fmaf(rc[s][k], v.y, cs);
        }
        const float2 me = sc[i];
        const float np = ph[i] + ep * (me.y * ss - me.x * cs);
        ph[i] = np;
        __builtin_nontemporal_store(np, op + i);
      }
    }
    ep = ep * (1.0f - 0.02f * (float)t);  // ep -= 0.5*t*ep/25
  }
}

extern "C" void kernel_launch(void* const* d_in, const int* in_sizes, int n_in,
                              void* d_out, int out_size, void* d_ws, size_t ws_size,
                              hipStream_t stream) {
  const float* input = (const float*)d_in[0];
  const float* ph0   = (const float*)d_in[1];
  const int*   conn  = (const int*)d_in[2];
  // d_in[3] = episodes (always 25)
  const float* w1 = (const float*)d_in[4];
  const float* b1 = (const float*)d_in[5];
  const float* w2 = (const float*)d_in[6];
  const float* b2 = (const float*)d_in[7];
  const float* w3 = (const float*)d_in[8];
  const float* b3 = (const float*)d_in[9];
  const float* fcw = (const float*)d_in[10];
  const float* fcb = (const float*)d_in[11];
  float* out = (float*)d_out;

  // workspace layout (bytes):
  // Abuf bf16 [0, 42467328) | Wbuf bf16 [42467328, 48660480) | w1t f32 [.., +288)
  // w2t bf16 [48660768, +3072) | w3t bf16 [48663840, +10240)
  ushort* Abuf = (ushort*)d_ws;
  ushort* Wbuf = (ushort*)((char*)d_ws + 42467328);
  float*  w1t  = (float*)((char*)d_ws + 48660480);
  ushort* w2t  = (ushort*)((char*)d_ws + 48660768);
  ushort* w3t  = (ushort*)((char*)d_ws + 48663840);
  float* fcout = out + PH_TOTAL;

  wprep_kernel<<<1, 256, 0, stream>>>(w1, w2, w3, w1t, w2t, w3t);
  wcvt_kernel<<<(FC_NPAD * FC_K) / 256, 256, 0, stream>>>(fcw, Wbuf);
  conv_fused_kernel<<<dim3(BATCH, 3), 256, 0, stream>>>(input, w1t, b1, w2t, b2, w3t, b3, Abuf);
  gemm_kernel<<<448, 256, 0, stream>>>(Abuf, Wbuf, fcb, fcout);
  kuramoto_kernel<<<BATCH, 512, 0, stream>>>(ph0, conn, fcout, out);
}

// Round 6
// 248.167 us; speedup vs baseline: 3.3855x; 1.0833x over previous
//
#include <hip/hip_runtime.h>
#include <hip/hip_bf16.h>

#define NPOS 1296              // 36*36 oscillators
#define BATCH 512
#define STEPS 25
#define PH_STRIDE (BATCH * NPOS)            // 663552
#define PH_TOTAL ((STEPS + 1) * PH_STRIDE)  // 17252352
#define FC_K 3456
#define FC_N 864
#define FC_NPAD 896
#define FC_M 6144
#define KT_ITERS 54            // FC_K / 64

typedef float f32x4 __attribute__((ext_vector_type(4)));
typedef __bf16 bf16x8 __attribute__((ext_vector_type(8)));

__device__ __forceinline__ ushort f2bf(float f) {
  union { float f; unsigned u; } v; v.f = f;
  unsigned r = v.u + 0x7FFFu + ((v.u >> 16) & 1u);  // RNE
  return (ushort)(r >> 16);
}
__device__ __forceinline__ float bf2f(ushort h) {
  union { unsigned u; float f; } v; v.u = ((unsigned)h) << 16; return v.f;
}

__device__ __forceinline__ void async_copy16(void* lds, const void* g) {
  __builtin_amdgcn_global_load_lds(
      (const __attribute__((address_space(1))) unsigned*)g,
      (__attribute__((address_space(3))) unsigned*)lds, 16, 0, 0);
}
__device__ __forceinline__ void raw_barrier() { asm volatile("s_barrier" ::: "memory"); }
__device__ __forceinline__ void waitcnt_vm7() { asm volatile("s_waitcnt vmcnt(7)" ::: "memory"); }
__device__ __forceinline__ void waitcnt_vm0() { asm volatile("s_waitcnt vmcnt(0)" ::: "memory"); }

// ---------------- weight prep: transpose to MFMA-friendly [co][k] layouts ----------------
__global__ __launch_bounds__(256) void wprep_kernel(
    const float* __restrict__ w1, const float* __restrict__ w2, const float* __restrict__ w3,
    float* __restrict__ w1t, ushort* __restrict__ w2t, ushort* __restrict__ w3t) {
  const int tid = threadIdx.x;
  for (int i = tid; i < 72; i += 256) {
    const int s = i / 8, co = i - s * 8;
    w1t[i] = w1[co * 9 + s];
  }
  for (int i = tid; i < 16 * 96; i += 256) {
    const int co = i / 96, k = i - co * 96;
    const int s = k / 8, ci = k - s * 8;
    w2t[i] = (k < 72) ? f2bf(w2[(co * 8 + ci) * 9 + s]) : (ushort)0;
  }
  for (int i = tid; i < 32 * 160; i += 256) {
    const int co = i / 160, k = i - co * 160;
    const int s = k / 16, ci = k - s * 16;
    w3t[i] = (k < 144) ? f2bf(w3[(co * 16 + ci) * 9 + s]) : (ushort)0;
  }
}

// ---------------- fused conv1(VALU) + conv2(MFMA) + conv3(MFMA+sigmoid) ----------------
__global__ __launch_bounds__(256, 4) void conv_fused_kernel(
    const float* __restrict__ in, const float* __restrict__ w1t, const float* __restrict__ b1,
    const ushort* __restrict__ w2t, const float* __restrict__ b2,
    const ushort* __restrict__ w3t, const float* __restrict__ b3,
    ushort* __restrict__ aout) {
  __shared__ __align__(16) float sIn[18][40];          // input rows r0-3..r0+14, col x at x+2
  __shared__ __align__(16) ushort sC1[18][40][8];      // c1 rows r0-2..r0+13 (rows 16,17 zero)
  __shared__ __align__(16) ushort sC2[16][40][16];     // c2 rows r0-1..r0+12 (rows 14,15 zero)
  const int b = blockIdx.x, band = blockIdx.y, tid = threadIdx.x;
  const int r0 = band * 12;
  const int wave = tid >> 6, lane = tid & 63;
  const int quad = lane >> 4, l16 = lane & 15;
  {
    const uint4 zz = make_uint4(0, 0, 0, 0);
    for (int i = tid; i < 180; i += 256) ((uint4*)sIn)[i] = zz;
    for (int i = tid; i < 720; i += 256) ((uint4*)sC1)[i] = zz;
    for (int i = tid; i < 1280; i += 256) ((uint4*)sC2)[i] = zz;
  }
  __syncthreads();
  for (int i = tid; i < 18 * 18; i += 256) {
    const int r = i / 18, c = i - r * 18;
    const int gy = r0 - 3 + r;
    if ((unsigned)gy < 36u)
      *(float2*)&sIn[r][2 + 2 * c] = *(const float2*)(in + (size_t)b * NPOS + gy * 36 + 2 * c);
  }
  __syncthreads();
  // conv1
  for (int i = tid; i < 16 * 36; i += 256) {
    const int lr = i / 36, x = i - lr * 36;
    float acc[8];
#pragma unroll
    for (int co = 0; co < 8; ++co) acc[co] = b1[co];
#pragma unroll
    for (int s = 0; s < 9; ++s) {
      const int dy = s / 3, dx = s - 3 * dy;
      const float v = sIn[lr + dy][x + 1 + dx];
#pragma unroll
      for (int co = 0; co < 8; ++co) acc[co] = fmaf(w1t[s * 8 + co], v, acc[co]);
    }
    const int g1 = r0 - 2 + lr;
    if ((unsigned)g1 < 36u) {
      uint4 pk;
      pk.x = (uint)f2bf(fmaxf(acc[0], 0.f)) | ((uint)f2bf(fmaxf(acc[1], 0.f)) << 16);
      pk.y = (uint)f2bf(fmaxf(acc[2], 0.f)) | ((uint)f2bf(fmaxf(acc[3], 0.f)) << 16);
      pk.z = (uint)f2bf(fmaxf(acc[4], 0.f)) | ((uint)f2bf(fmaxf(acc[5], 0.f)) << 16);
      pk.w = (uint)f2bf(fmaxf(acc[6], 0.f)) | ((uint)f2bf(fmaxf(acc[7], 0.f)) << 16);
      *(uint4*)&sC1[lr][x + 2][0] = pk;
    }
  }
  __syncthreads();
  // conv2 via MFMA: M=512 px, N=16 co, K=96 (72 real)
  bf16x8 w2f[3];
#pragma unroll
  for (int f = 0; f < 3; ++f)
    w2f[f] = *(const bf16x8*)(w2t + l16 * 96 + f * 32 + quad * 8);
  const float bias2 = b2[l16];
  for (int chunk = wave; chunk < 32; chunk += 4) {
    const int m = chunk * 16 + l16;
    const int oy = m / 36, x = m - oy * 36;
    f32x4 acc = {0.f, 0.f, 0.f, 0.f};
#pragma unroll
    for (int f = 0; f < 3; ++f) {
      const int s0 = 4 * f + quad;
      const int dy = s0 / 3, dx = s0 - 3 * dy;
      const bf16x8 af = *(const bf16x8*)&sC1[oy + dy][x + 1 + dx][0];
      acc = __builtin_amdgcn_mfma_f32_16x16x32_bf16(af, w2f[f], acc, 0, 0, 0);
    }
#pragma unroll
    for (int r = 0; r < 4; ++r) {
      const int px = chunk * 16 + quad * 4 + r;
      const int oy2 = px / 36, x2 = px - oy2 * 36;
      const int g2 = r0 - 1 + oy2;
      if (px < 504 && (unsigned)g2 < 36u)
        sC2[oy2][x2 + 2][l16] = f2bf(fmaxf(acc[r] + bias2, 0.f));
    }
  }
  __syncthreads();
  // conv3 via MFMA: M=432 px, N=32 co (2 tiles), K=160 (144 real)
  bf16x8 w3f[2][5];
#pragma unroll
  for (int t = 0; t < 2; ++t)
#pragma unroll
    for (int f = 0; f < 5; ++f)
      w3f[t][f] = *(const bf16x8*)(w3t + (t * 16 + l16) * 160 + f * 32 + quad * 8);
  const float bias3a = b3[l16], bias3b = b3[16 + l16];
  ushort* ob = aout + (size_t)b * (32 * NPOS) + r0 * 36;
  for (int chunk = wave; chunk < 27; chunk += 4) {
    const int m = chunk * 16 + l16;
    const int oy = m / 36, x = m - oy * 36;
    f32x4 acc0 = {0.f, 0.f, 0.f, 0.f}, acc1 = {0.f, 0.f, 0.f, 0.f};
#pragma unroll
    for (int f = 0; f < 5; ++f) {
      const int s0 = 2 * f + (quad >> 1);
      const int dy = s0 / 3, dx = s0 - 3 * dy;
      const bf16x8 af = *(const bf16x8*)&sC2[oy + dy][x + 1 + dx][(quad & 1) * 8];
      acc0 = __builtin_amdgcn_mfma_f32_16x16x32_bf16(af, w3f[0][f], acc0, 0, 0, 0);
      acc1 = __builtin_amdgcn_mfma_f32_16x16x32_bf16(af, w3f[1][f], acc1, 0, 0, 0);
    }
    const int pxb = chunk * 16 + quad * 4;
    ushort4 pk;
#pragma unroll
    for (int r = 0; r < 4; ++r)
      ((ushort*)&pk)[r] = f2bf(1.f / (1.f + __expf(-(acc0[r] + bias3a))));
    *(ushort4*)(ob + (size_t)l16 * NPOS + pxb) = pk;
#pragma unroll
    for (int r = 0; r < 4; ++r)
      ((ushort*)&pk)[r] = f2bf(1.f / (1.f + __expf(-(acc1[r] + bias3b))));
    *(ushort4*)(ob + (size_t)(16 + l16) * NPOS + pxb) = pk;
  }
}

// ---------------- fc_w (864x3456 f32) -> bf16, rows padded to 896 with zeros ----------------
__global__ __launch_bounds__(256) void wcvt_kernel(const float* __restrict__ w, ushort* __restrict__ wb) {
  const int idx = blockIdx.x * 256 + threadIdx.x;
  if (idx >= FC_NPAD * FC_K) return;
  const int n = idx / FC_K;
  wb[idx] = (n < FC_N) ? f2bf(w[idx]) : (ushort)0;
}

// ---------------- bf16 NT GEMM: C[m][n] = sum_k A[m][k]*Bt[n][k] + bias[n] ----------------
// 96x128 block tile, 4 waves of 48x64 (3x4 acc). Double-buffered LDS tiles, raw s_barrier +
// s_waitcnt vmcnt(7) prefetch pipeline (tile kt+2 in flight during compute of kt+1).
// LDS cells XOR-swizzled (octet o of row r at slot o^((r>>1)&3)) -> conflict-free b128 reads
// while keeping global_load_lds lane-linear dests and 64B-coalesced sources.
__global__ __launch_bounds__(256) void gemm_kernel(
    const ushort* __restrict__ A, const ushort* __restrict__ Bt,
    const float* __restrict__ bias, float* __restrict__ C) {
  // buffer p: A slab s at [p][s*3072 + (r*4+o')*8], B slab s at [p][6144 + s*4096 + (r*4+o')*8]
  __shared__ __align__(16) ushort smem[2][14336];
  const int tid = threadIdx.x;
  const int lin = blockIdx.x;
  const int xcd = lin & 7, g = lin >> 3;           // 448 blocks
  const int bn = g % 7;
  const int bm = xcd + 8 * (g / 7);                // 0..63
  const int row0 = bm * 96, col0 = bn * 128;
  const int wave = tid >> 6, lane = tid & 63;
  const int wr = (wave >> 1) * 48, wc = (wave & 1) * 64;
  const int quad = lane >> 4, l16 = lane & 15;
  const int oswz = (quad ^ ((l16 >> 1) & 3)) * 8;  // swizzled octet offset for fragment reads
  f32x4 acc[3][4] = {};

  // staging descriptors: 7 chunks/wave, chunk = 16 rows x 4 octets (64 lanes x 16B)
  const int rr = lane >> 2;                              // row within chunk
  const int soct = ((lane & 3) ^ ((lane >> 3) & 3)) * 8; // source k-octet (elems)
  const ushort* gsrc[7];
  const ushort* ldst[7];
  {
    const int s = wave >> 1;  // slab this wave-pair stages
    if ((wave & 1) == 0) {
      // 6 A-chunks + B-chunk 0 of slab s
#pragma unroll
      for (int j = 0; j < 6; ++j) {
        gsrc[j] = A + ((size_t)row0 + j * 16 + rr) * FC_K + s * 32 + soct;
        ldst[j] = &smem[0][s * 3072 + j * 512];
      }
      gsrc[6] = Bt + ((size_t)col0 + rr) * FC_K + s * 32 + soct;
      ldst[6] = &smem[0][6144 + s * 4096];
    } else {
      // B-chunks 1..7 of slab s
#pragma unroll
      for (int j = 0; j < 7; ++j) {
        gsrc[j] = Bt + ((size_t)col0 + (j + 1) * 16 + rr) * FC_K + s * 32 + soct;
        ldst[j] = &smem[0][6144 + s * 4096 + (j + 1) * 512];
      }
    }
  }
  // prologue: tiles 0 and 1 in flight
#pragma unroll
  for (int j = 0; j < 7; ++j) async_copy16((void*)ldst[j], gsrc[j]);
#pragma unroll
  for (int j = 0; j < 7; ++j) async_copy16((void*)(ldst[j] + 14336), gsrc[j] + 64);

  for (int kt = 0; kt < KT_ITERS; ++kt) {
    const int p = kt & 1;
    waitcnt_vm7();          // oldest 7 (this tile's chunks) complete; prefetch stays in flight
    raw_barrier();
    const ushort* base = &smem[p][0];
#pragma unroll
    for (int s = 0; s < 2; ++s) {
      bf16x8 af[3], bfr[4];
#pragma unroll
      for (int t = 0; t < 3; ++t)
        af[t] = *(const bf16x8*)(base + s * 3072 + (wr + t * 16 + l16) * 32 + oswz);
#pragma unroll
      for (int t = 0; t < 4; ++t)
        bfr[t] = *(const bf16x8*)(base + 6144 + s * 4096 + (wc + t * 16 + l16) * 32 + oswz);
#pragma unroll
      for (int tm = 0; tm < 3; ++tm)
#pragma unroll
        for (int tn = 0; tn < 4; ++tn)
          acc[tm][tn] = __builtin_amdgcn_mfma_f32_16x16x32_bf16(af[tm], bfr[tn], acc[tm][tn], 0, 0, 0);
    }
    raw_barrier();          // everyone done reading buffer p
    int kn = kt + 2;
    if (kn >= KT_ITERS) kn -= KT_ITERS;   // wrap: harmless extra tile keeps vmcnt uniform
    const int koff = kn * 64;
#pragma unroll
    for (int j = 0; j < 7; ++j) async_copy16((void*)(ldst[j] + p * 14336), gsrc[j] + koff);
  }
  waitcnt_vm0();            // drain dangling wrap copies before workgroup end

#pragma unroll
  for (int tn = 0; tn < 4; ++tn) {
    const int col = col0 + wc + tn * 16 + l16;
    if (col < FC_N) {
      const float bv = bias[col];
#pragma unroll
      for (int tm = 0; tm < 3; ++tm) {
#pragma unroll
        for (int r = 0; r < 4; ++r) {
          const int row = row0 + wr + tm * 16 + quad * 4 + r;
          C[(size_t)row * FC_N + col] = acc[tm][tn][r] + bv;
        }
      }
    }
  }
}

// ---------------- Kuramoto: one block (512 threads) per batch, 25 steps ----------------
// Phases + own sin/cos in registers; double-buffered sc -> ONE barrier per step.
__global__ __launch_bounds__(512) void kuramoto_kernel(
    const float* __restrict__ ph0, const int* __restrict__ conn,
    const float* __restrict__ cpl, float* __restrict__ out) {
  __shared__ float2 sc[2][NPOS];
  const int b = blockIdx.x, tid = threadIdx.x;
  int rj[3][8];
  float rc[3][8];
  float myph[3];
  float2 mysc[3];
#pragma unroll
  for (int s = 0; s < 3; ++s) {
    const int i = tid + s * 512;
    if (i < NPOS) {
      const float p = ph0[(size_t)b * NPOS + i];
      myph[s] = p;
      __builtin_nontemporal_store(p, out + (size_t)b * NPOS + i);  // step 0
      float sn, cn;
      __sincosf(p, &sn, &cn);
      mysc[s] = make_float2(sn, cn);
      sc[0][i] = mysc[s];
      const size_t base = (size_t)b * (NPOS * 8) + (size_t)i * 8;
      const int4 j0 = *(const int4*)(conn + base);
      const int4 j1 = *(const int4*)(conn + base + 4);
      const float4 c0 = *(const float4*)(cpl + base);
      const float4 c1 = *(const float4*)(cpl + base + 4);
      rj[s][0] = j0.x; rj[s][1] = j0.y; rj[s][2] = j0.z; rj[s][3] = j0.w;
      rj[s][4] = j1.x; rj[s][5] = j1.y; rj[s][6] = j1.z; rj[s][7] = j1.w;
      rc[s][0] = c0.x; rc[s][1] = c0.y; rc[s][2] = c0.z; rc[s][3] = c0.w;
      rc[s][4] = c1.x; rc[s][5] = c1.y; rc[s][6] = c1.z; rc[s][7] = c1.w;
    }
  }
  float ep = 0.1f;
  for (int t = 0; t < STEPS; ++t) {
    __syncthreads();          // step t-1's sc writes visible
    const int cur = t & 1;
    float* op = out + (size_t)(t + 1) * PH_STRIDE + (size_t)b * NPOS;
#pragma unroll
    for (int s = 0; s < 3; ++s) {
      const int i = tid + s * 512;
      if (i < NPOS) {
        float ss = 0.f, cc = 0.f;
#pragma unroll
        for (int k = 0; k < 8; ++k) {
          const float2 v = sc[cur][rj[s][k]];
          ss = fmaf(rc[s][k], v.x, ss);
          cc = fmaf(rc[s][k], v.y, cc);
        }
        const float np = myph[s] + ep * (mysc[s].y * ss - mysc[s].x * cc);
        myph[s] = np;
        __builtin_nontemporal_store(np, op + i);
        float sn, cn;
        __sincosf(np, &sn, &cn);
        mysc[s] = make_float2(sn, cn);
        sc[cur ^ 1][i] = mysc[s];   // other buffer: no race with this step's gathers
      }
    }
    ep = ep * (1.0f - 0.02f * (float)t);  // ep -= 0.5*t*ep/25
  }
}

extern "C" void kernel_launch(void* const* d_in, const int* in_sizes, int n_in,
                              void* d_out, int out_size, void* d_ws, size_t ws_size,
                              hipStream_t stream) {
  const float* input = (const float*)d_in[0];
  const float* ph0   = (const float*)d_in[1];
  const int*   conn  = (const int*)d_in[2];
  // d_in[3] = episodes (always 25)
  const float* w1 = (const float*)d_in[4];
  const float* b1 = (const float*)d_in[5];
  const float* w2 = (const float*)d_in[6];
  const float* b2 = (const float*)d_in[7];
  const float* w3 = (const float*)d_in[8];
  const float* b3 = (const float*)d_in[9];
  const float* fcw = (const float*)d_in[10];
  const float* fcb = (const float*)d_in[11];
  float* out = (float*)d_out;

  // workspace layout (bytes):
  // Abuf bf16 [0, 42467328) | Wbuf bf16 [42467328, 48660480) | w1t f32 [.., +288)
  // w2t bf16 [48660768, +3072) | w3t bf16 [48663840, +10240)
  ushort* Abuf = (ushort*)d_ws;
  ushort* Wbuf = (ushort*)((char*)d_ws + 42467328);
  float*  w1t  = (float*)((char*)d_ws + 48660480);
  ushort* w2t  = (ushort*)((char*)d_ws + 48660768);
  ushort* w3t  = (ushort*)((char*)d_ws + 48663840);
  float* fcout = out + PH_TOTAL;

  wprep_kernel<<<1, 256, 0, stream>>>(w1, w2, w3, w1t, w2t, w3t);
  wcvt_kernel<<<(FC_NPAD * FC_K) / 256, 256, 0, stream>>>(fcw, Wbuf);
  conv_fused_kernel<<<dim3(BATCH, 3), 256, 0, stream>>>(input, w1t, b1, w2t, b2, w3t, b3, Abuf);
  gemm_kernel<<<448, 256, 0, stream>>>(Abuf, Wbuf, fcb, fcout);
  kuramoto_kernel<<<BATCH, 512, 0, stream>>>(ph0, conn, fcout, out);
}